// Round 8
// baseline (664.013 us; speedup 1.0000x reference)
//
#include <hip/hip_runtime.h>
#include <hip/hip_bf16.h>

// ---------------------------------------------------------------------------
// Sudoku GCN, fully fused, MFMA-everything.
//   h_{l+1} = relu( (A+I) h_l * (W_l/21) + b_l ),  A+I exact 0/1 in bf16.
// Orientation ping-pong (no transposed reads, all epi writes b64-packed):
//   hbuf = h^T [feat][node] (chunk-major), gbuf = g [node][feat] (chunk-major)
//   agg : g^T = h^T (A+I)     reads hbuf rows, writes gbuf packed
//   gemm: h'  = g (W/21)      reads gbuf rows, writes hbuf packed
//   l=6 : h6^T = W^T g^T      writes h6 as [node][feat] for the output GEMM
// Layer 1 collapsed: h1 = relu(Cnt @ U + b1), U = relu(Win+bin)@W1/21.
// R8: LDS-throughput fix (R7 is LDS-pipe-bound: ~45K of 53.8K cyc/block,
// ~736 KB/layer). 768 threads = 12 waves, each wave owns a 2x2 tile job in
// EVERY phase (12 jobs exactly). Operand reads amortize over 2 tiles each:
// ~390 KB/layer (1.9x less). At 3 waves/SIMD the VGPR cap is 170 (vs 128 at
// 1024 thr), so A+I frags live in registers again (abf 24 + wbf 64 + acc 16
// + temps ~130 < 170, no spill). Layouts/numerics identical to R7.
// ---------------------------------------------------------------------------

typedef short          s16x8 __attribute__((ext_vector_type(8)));
typedef unsigned short u16x8 __attribute__((ext_vector_type(8)));
typedef unsigned short u16x4 __attribute__((ext_vector_type(4)));
typedef float          f32x4 __attribute__((ext_vector_type(4)));

#define HB   0        // hbuf: [2 pl][12 chunk][128 feat][16B]  plane stride 24576
#define GB   49152    // gbuf: [2 pl][16 chunk][96 node][16B]   plane stride 24576
#define CNT  98304    // cnt : [4 chunk][96 node][16B] = 6144
#define XC   104448   // x cache: 81 ints
#define LDS_SZ 104832

#define OFF_WB   5120     // [l 0..4][nt 0..7][ks 0..3][pl 0..1] x 1024B
#define OFF_AB   332800   // [nt 0..5][ks 0..2] x 1024B  (A+I, hi only, exact)
#define OFF_UB   351232   // [nt 0..7][pl] x 1024B
#define OFF_WOUT 367616   // [ks 0..3][pl] x 1024B
#define WS_NEED  375808

__device__ __forceinline__ unsigned short f2bf(float f) {   // RTNE via v_cvt
  return __builtin_bit_cast(unsigned short, __float2bfloat16(f));
}
__device__ __forceinline__ float bf2f(unsigned short h) {
  unsigned u = ((unsigned)h) << 16;
  return __builtin_bit_cast(float, u);
}
__device__ __forceinline__ f32x4 mfma16(u16x8 a, u16x8 b, f32x4 c) {
  return __builtin_amdgcn_mfma_f32_16x16x32_bf16(
      __builtin_bit_cast(s16x8, a), __builtin_bit_cast(s16x8, b), c, 0, 0, 0);
}
__device__ __forceinline__ void split4(f32x4 v, u16x4& hi, u16x4& lo) {
#pragma unroll
  for (int r = 0; r < 4; ++r) {
    unsigned short h = f2bf(v[r]);
    hi[r] = h;
    lo[r] = f2bf(v[r] - bf2f(h));
  }
}
__device__ __forceinline__ bool adjf(int r, int c) {
  if (r >= 81 || c >= 81) return false;
  int ri = r / 9, rj = r % 9, ci = c / 9, cj = c % 9;
  return ri == ci || rj == cj || (ri / 3 == ci / 3 && rj / 3 == cj / 3);
}
__device__ __forceinline__ u16x8 makeAB(int nt, int ks, int lane) {
  int col = nt * 16 + (lane & 15), k0 = ks * 32 + (lane >> 4) * 8;
  u16x8 r;
#pragma unroll
  for (int i = 0; i < 8; ++i) r[i] = adjf(k0 + i, col) ? 0x3F80 : 0;
  return r;
}

// ---------------- setup1: U[10][128] = relu(Win+bin) @ W1 / 21 (f32, ws+0) ---
extern "C" __global__ void gnn_setup(const float* __restrict__ Win,
                                     const float* __restrict__ bin,
                                     const float* __restrict__ W1,
                                     float* __restrict__ U) {
  __shared__ float V[1280];
  int t = threadIdx.x;
#pragma unroll
  for (int q = 0; q < 5; ++q) {
    int idx = t + 256 * q;
    V[idx] = fmaxf(Win[idx] + bin[idx & 127], 0.f);
  }
  __syncthreads();
#pragma unroll
  for (int p = 0; p < 5; ++p) {
    int o = t + 256 * p;
    int d = o >> 7, c = o & 127;
    float s = 0.f;
    for (int f = 0; f < 128; ++f) s += V[d * 128 + f] * W1[f * 128 + c];
    U[o] = s * (1.f / 21.f);
  }
}

// ---------------- setup2: pack all B/A fragment blobs into ws ----------------
extern "C" __global__ void gnn_pack(const float* __restrict__ Wl,
                                    const float* __restrict__ Wout,
                                    const float* __restrict__ Uscr,
                                    char* __restrict__ G) {
  int unit = blockIdx.x, lane = threadIdx.x;
  int rsel = lane & 15, kh = lane >> 4;
  u16x8 r;
  char* dst;
  if (unit < 320) {                       // WB: ((l*8+nt)*4+ks)*2+pl
    int pl = unit & 1, ks = (unit >> 1) & 3, nt = (unit >> 3) & 7, l = unit >> 6;
    int col = nt * 16 + rsel, k0 = ks * 32 + kh * 8;
    const float* src = Wl + (l + 1) * 16384 + k0 * 128 + col;
#pragma unroll
    for (int i = 0; i < 8; ++i) {
      float v = src[i * 128] * (1.f / 21.f);
      unsigned short h = f2bf(v);
      r[i] = pl ? f2bf(v - bf2f(h)) : h;
    }
    dst = G + OFF_WB + unit * 1024 + lane * 16;
  } else if (unit < 338) {                // AB: nt*3+ks
    int u2 = unit - 320, nt = u2 / 3, ks = u2 % 3;
    r = makeAB(nt, ks, lane);
    dst = G + OFF_AB + u2 * 1024 + lane * 16;
  } else if (unit < 354) {                // UB: nt*2+pl
    int u2 = unit - 338, nt = u2 >> 1, pl = u2 & 1;
    int col = nt * 16 + rsel;
#pragma unroll
    for (int i = 0; i < 8; ++i) {
      int k = kh * 8 + i;
      float v = (k < 10) ? Uscr[k * 128 + col] : 0.f;
      unsigned short h = f2bf(v);
      r[i] = pl ? f2bf(v - bf2f(h)) : h;
    }
    dst = G + OFF_UB + u2 * 1024 + lane * 16;
  } else {                                // WOUT: ks*2+pl
    int u2 = unit - 354, ks = u2 >> 1, pl = u2 & 1;
    int col = rsel, k0 = ks * 32 + kh * 8;
#pragma unroll
    for (int i = 0; i < 8; ++i) {
      float v = (col < 9) ? Wout[(k0 + i) * 9 + col] : 0.f;
      unsigned short h = f2bf(v);
      r[i] = pl ? f2bf(v - bf2f(h)) : h;
    }
    dst = G + OFF_WOUT + u2 * 1024 + lane * 16;
  }
  *(u16x8*)dst = r;
}

// --------------------------------- main -------------------------------------
template <bool PRE>
__global__ void __launch_bounds__(768, 3)
gnn_main(const int* __restrict__ x, const float* __restrict__ Wl,
         const float* __restrict__ bl, const float* __restrict__ Wout,
         const float* __restrict__ bout, const float* __restrict__ ws,
         float* __restrict__ out, int nB) {
  extern __shared__ char lds[];
  const int t = threadIdx.x, lane = t & 63, w = t >> 6;   // w 0..11
  const int rsel = lane & 15, kh = lane >> 4;
  const char* G = (const char*)ws;
  const int b = blockIdx.x;

  // 2x2-tile wave mapping, uniform for ALL phases:
  const int mg = w % 3;                  // node-tile group: tiles mg*2+{0,1} of 6
  const int fg = w / 3;                  // feat-tile group: tiles fg*2+{0,1} of 8

  // ---- persistent A+I B-frags for this wave's 2 node-tiles: 24 VGPRs ----
  u16x8 abf[2][3];                       // [jn][ks]
#pragma unroll
  for (int jn = 0; jn < 2; ++jn)
#pragma unroll
    for (int ks = 0; ks < 3; ++ks) {
      if constexpr (PRE)
        abf[jn][ks] = *(const u16x8*)(G + OFF_AB + (((mg * 2 + jn) * 3 + ks) << 10) + lane * 16);
      else
        abf[jn][ks] = makeAB(mg * 2 + jn, ks, lane);
    }

  // per-phase W frags: [jf][ks][pl] = 16 frags = 64 VGPRs
  u16x8 wbf[2][4][2];
  auto loadWB = [&](int blob) {
#pragma unroll
    for (int jf = 0; jf < 2; ++jf)
#pragma unroll
      for (int ks = 0; ks < 4; ++ks)
#pragma unroll
        for (int pl = 0; pl < 2; ++pl) {
          if constexpr (PRE) {
            wbf[jf][ks][pl] = *(const u16x8*)(
                G + OFF_WB + ((((blob * 8 + (fg * 2 + jf)) * 4 + ks) * 2 + pl) << 10) + lane * 16);
          } else {
            int colw = (fg * 2 + jf) * 16 + rsel, k0 = ks * 32 + kh * 8;
            const float* src = Wl + (blob + 1) * 16384 + k0 * 128 + colw;
            u16x8 r;
#pragma unroll
            for (int i = 0; i < 8; ++i) {
              float v = src[i * 128] * (1.f / 21.f);
              unsigned short h = f2bf(v);
              r[i] = pl ? f2bf(v - bf2f(h)) : h;
            }
            wbf[jf][ks][pl] = r;
          }
        }
  };

  // ---- x cache + digit counts -> cntbuf ----
  if (t < 81) ((int*)(lds + XC))[t] = x[b * 81 + t];
  __syncthreads();
  if (t < 96) {
    unsigned short cnt[16];
#pragma unroll
    for (int d = 0; d < 16; ++d) cnt[d] = 0;
    if (t < 81) {
      const int* xs = (const int*)(lds + XC);
      int n = t, i = n / 9, j = n - 9 * i;
      int bi = (i / 3) * 3, bj = (j / 3) * 3;
      int rv[9], cv[9], bv[9], rb3[3], cb3[3];
#pragma unroll
      for (int k = 0; k < 9; ++k) rv[k] = xs[i * 9 + k];
#pragma unroll
      for (int k = 0; k < 9; ++k) cv[k] = xs[k * 9 + j];
#pragma unroll
      for (int r2 = 0; r2 < 3; ++r2)
#pragma unroll
        for (int c2 = 0; c2 < 3; ++c2) bv[r2 * 3 + c2] = xs[(bi + r2) * 9 + (bj + c2)];
#pragma unroll
      for (int k = 0; k < 3; ++k) rb3[k] = xs[i * 9 + bj + k];
#pragma unroll
      for (int k = 0; k < 3; ++k) cb3[k] = xs[(bi + k) * 9 + j];
#pragma unroll
      for (int d = 0; d < 10; ++d) {
        int c = 0;
#pragma unroll
        for (int k = 0; k < 9; ++k) c += (rv[k] == d) + (cv[k] == d) + (bv[k] == d);
#pragma unroll
        for (int k = 0; k < 3; ++k) c -= (rb3[k] == d) + (cb3[k] == d);
        cnt[d] = f2bf((float)c);         // integers <=21: exact in bf16
      }
    }
    u16x8 c0, c1, z;
#pragma unroll
    for (int e = 0; e < 8; ++e) { c0[e] = cnt[e]; c1[e] = cnt[8 + e]; z[e] = 0; }
    *(u16x8*)(lds + CNT + 0 * 1536 + t * 16) = c0;
    *(u16x8*)(lds + CNT + 1 * 1536 + t * 16) = c1;
    *(u16x8*)(lds + CNT + 2 * 1536 + t * 16) = z;
    *(u16x8*)(lds + CNT + 3 * 1536 + t * 16) = z;
  }
  __syncthreads();

  // ---- L1 GEMM: h1 = relu(Cnt @ U + b1) -> hbuf [feat][node] (2x2 tiles) ----
  {
    u16x8 ubf[2][2];                     // [jf][pl] (dead after L1)
#pragma unroll
    for (int jf = 0; jf < 2; ++jf)
#pragma unroll
      for (int pl = 0; pl < 2; ++pl) {
        if constexpr (PRE)
          ubf[jf][pl] = *(const u16x8*)(G + OFF_UB + (((fg * 2 + jf) * 2 + pl) << 10) + lane * 16);
        else {
          int col = (fg * 2 + jf) * 16 + rsel;
          u16x8 r;
#pragma unroll
          for (int i = 0; i < 8; ++i) {
            int k = kh * 8 + i;
            float v = (k < 10) ? ws[k * 128 + col] : 0.f;
            unsigned short h = f2bf(v);
            r[i] = pl ? f2bf(v - bf2f(h)) : h;
          }
          ubf[jf][pl] = r;
        }
      }
    float bL1[2];
#pragma unroll
    for (int jf = 0; jf < 2; ++jf) bL1[jf] = bl[(fg * 2 + jf) * 16 + rsel];

    f32x4 a1[2][2];                      // [jn][jf]
#pragma unroll
    for (int jn = 0; jn < 2; ++jn)
#pragma unroll
      for (int jf = 0; jf < 2; ++jf) a1[jn][jf] = f32x4{0.f, 0.f, 0.f, 0.f};
#pragma unroll
    for (int jn = 0; jn < 2; ++jn) {
      int node = (mg * 2 + jn) * 16 + rsel;
      u16x8 af = *(const u16x8*)(lds + CNT + kh * 1536 + node * 16);
#pragma unroll
      for (int jf = 0; jf < 2; ++jf) {
        a1[jn][jf] = mfma16(af, ubf[jf][0], a1[jn][jf]);
        a1[jn][jf] = mfma16(af, ubf[jf][1], a1[jn][jf]);
      }
    }
#pragma unroll
    for (int jn = 0; jn < 2; ++jn)
#pragma unroll
      for (int jf = 0; jf < 2; ++jf) {
        int node0 = (mg * 2 + jn) * 16 + kh * 4;
        int feat = (fg * 2 + jf) * 16 + rsel;
        f32x4 v;
#pragma unroll
        for (int r = 0; r < 4; ++r) {
          float u = fmaxf(a1[jn][jf][r] + bL1[jf], 0.f);
          v[r] = (node0 + r < 81) ? u : 0.f;
        }
        u16x4 hi, lo;
        split4(v, hi, lo);
        int base = (node0 >> 3) * 2048 + feat * 16 + (node0 & 7) * 2;
        *(u16x4*)(lds + HB + base) = hi;
        *(u16x4*)(lds + HB + 24576 + base) = lo;
      }
  }

  // agg: g^T = h^T (A+I)  (A+I exact from regs, h hi/lo -> 2 products)
  auto do_agg = [&]() {
    f32x4 ag[2][2];                      // [jm(feat)][jn(node)]
#pragma unroll
    for (int jm = 0; jm < 2; ++jm)
#pragma unroll
      for (int jn = 0; jn < 2; ++jn) ag[jm][jn] = f32x4{0.f, 0.f, 0.f, 0.f};
#pragma unroll
    for (int ks = 0; ks < 3; ++ks) {
#pragma unroll
      for (int jm = 0; jm < 2; ++jm) {
        int feat = (fg * 2 + jm) * 16 + rsel;
        int ba = (ks * 4 + kh) * 2048 + feat * 16;
        u16x8 ah = *(const u16x8*)(lds + HB + ba);
        u16x8 al = *(const u16x8*)(lds + HB + 24576 + ba);
#pragma unroll
        for (int jn = 0; jn < 2; ++jn) {
          ag[jm][jn] = mfma16(ah, abf[jn][ks], ag[jm][jn]);
          ag[jm][jn] = mfma16(al, abf[jn][ks], ag[jm][jn]);
        }
      }
    }
#pragma unroll
    for (int jm = 0; jm < 2; ++jm)
#pragma unroll
      for (int jn = 0; jn < 2; ++jn) {
        int node = (mg * 2 + jn) * 16 + rsel;
        int f0 = (fg * 2 + jm) * 16 + kh * 4;
        u16x4 hi, lo;
        split4(ag[jm][jn], hi, lo);
        int base = (f0 >> 3) * 1536 + node * 16 + (f0 & 7) * 2;
        *(u16x4*)(lds + GB + base) = hi;
        *(u16x4*)(lds + GB + 24576 + base) = lo;
      }
  };

  // ---- GCN layers 2..5 (uniform orientation; l==5 peeled below) ----
#pragma unroll 1
  for (int l = 1; l <= 4; ++l) {
    __syncthreads();                     // hbuf ready; gbuf free
    float bw[2];
#pragma unroll
    for (int jf = 0; jf < 2; ++jf) bw[jf] = bl[l * 128 + (fg * 2 + jf) * 16 + rsel];

    loadWB(l - 1);                       // issue early: latency hides under agg
    do_agg();
    __syncthreads();                     // gbuf ready; hbuf free

    // W-GEMM: h' = g (W/21): 3-product hi/lo; one gh/gl pair live at a time
    f32x4 wc[2][2];                      // [jm(node)][jf]
#pragma unroll
    for (int jm = 0; jm < 2; ++jm)
#pragma unroll
      for (int jf = 0; jf < 2; ++jf) wc[jm][jf] = f32x4{0.f, 0.f, 0.f, 0.f};
#pragma unroll
    for (int ks = 0; ks < 4; ++ks) {
#pragma unroll
      for (int jm = 0; jm < 2; ++jm) {
        int node = (mg * 2 + jm) * 16 + rsel;
        int ba = (ks * 4 + kh) * 1536 + node * 16;
        u16x8 gh = *(const u16x8*)(lds + GB + ba);
        u16x8 gl = *(const u16x8*)(lds + GB + 24576 + ba);
#pragma unroll
        for (int jf = 0; jf < 2; ++jf) {
          wc[jm][jf] = mfma16(gh, wbf[jf][ks][0], wc[jm][jf]);
          wc[jm][jf] = mfma16(gh, wbf[jf][ks][1], wc[jm][jf]);
          wc[jm][jf] = mfma16(gl, wbf[jf][ks][0], wc[jm][jf]);
        }
      }
    }
    // epi: bias+relu+mask -> hbuf [feat][node]
#pragma unroll
    for (int jm = 0; jm < 2; ++jm)
#pragma unroll
      for (int jf = 0; jf < 2; ++jf) {
        int node0 = (mg * 2 + jm) * 16 + kh * 4;
        int feat = (fg * 2 + jf) * 16 + rsel;
        f32x4 v;
#pragma unroll
        for (int r = 0; r < 4; ++r) {
          float u = fmaxf(wc[jm][jf][r] + bw[jf], 0.f);
          v[r] = (node0 + r < 81) ? u : 0.f;
        }
        u16x4 hi, lo;
        split4(v, hi, lo);
        int base = (node0 >> 3) * 2048 + feat * 16 + (node0 & 7) * 2;
        *(u16x4*)(lds + HB + base) = hi;
        *(u16x4*)(lds + HB + 24576 + base) = lo;
      }
  }

  // ---- layer 6 (l==5), peeled: agg, then flipped h6^T = (W/21)^T g^T ----
  __syncthreads();                       // hbuf ready
  loadWB(4);                             // flip weights; hides under agg
  do_agg();
  __syncthreads();                       // gbuf ready; hbuf free

  {
    float b5[2][4];
#pragma unroll
    for (int jf = 0; jf < 2; ++jf)
#pragma unroll
      for (int r = 0; r < 4; ++r)
        b5[jf][r] = bl[5 * 128 + (fg * 2 + jf) * 16 + kh * 4 + r];
    f32x4 wc[2][2];                      // [jf(feat-m)][jn(node-n)]
#pragma unroll
    for (int jf = 0; jf < 2; ++jf)
#pragma unroll
      for (int jn = 0; jn < 2; ++jn) wc[jf][jn] = f32x4{0.f, 0.f, 0.f, 0.f};
#pragma unroll
    for (int ks = 0; ks < 4; ++ks) {
#pragma unroll
      for (int jn = 0; jn < 2; ++jn) {
        int node = (mg * 2 + jn) * 16 + rsel;
        int ba = (ks * 4 + kh) * 1536 + node * 16;
        u16x8 gh = *(const u16x8*)(lds + GB + ba);
        u16x8 gl = *(const u16x8*)(lds + GB + 24576 + ba);
#pragma unroll
        for (int jf = 0; jf < 2; ++jf) {
          wc[jf][jn] = mfma16(wbf[jf][ks][0], gh, wc[jf][jn]);
          wc[jf][jn] = mfma16(wbf[jf][ks][0], gl, wc[jf][jn]);
          wc[jf][jn] = mfma16(wbf[jf][ks][1], gh, wc[jf][jn]);
        }
      }
    }
    // epi: C row=outfeat(4 consec), col=node -> h6buf[node][feat] b64-packed
#pragma unroll
    for (int jf = 0; jf < 2; ++jf)
#pragma unroll
      for (int jn = 0; jn < 2; ++jn) {
        int node = (mg * 2 + jn) * 16 + rsel;
        int f0 = (fg * 2 + jf) * 16 + kh * 4;
        f32x4 v;
#pragma unroll
        for (int r = 0; r < 4; ++r) {
          float u = fmaxf(wc[jf][jn][r] + b5[jf][r], 0.f);
          v[r] = (node < 81) ? u : 0.f;
        }
        u16x4 hi, lo;
        split4(v, hi, lo);
        int base = (f0 >> 3) * 1536 + node * 16 + (f0 & 7) * 2;
        *(u16x4*)(lds + HB + base) = hi;
        *(u16x4*)(lds + HB + 24576 + base) = lo;
      }
  }

  // ---- output GEMM: logits = h6 @ Wout + bout (waves 0..5, 1 tile each) ----
  u16x8 wo[4][2];                        // loaded AFTER flip (gh/gl/wc dead)
  if (w < 6) {
#pragma unroll
    for (int ks = 0; ks < 4; ++ks)
#pragma unroll
      for (int pl = 0; pl < 2; ++pl) {
        if constexpr (PRE)
          wo[ks][pl] = *(const u16x8*)(G + OFF_WOUT + (ks * 2 + pl) * 1024 + lane * 16);
        else {
          int col = rsel, k0 = ks * 32 + kh * 8;
          u16x8 r;
#pragma unroll
          for (int i = 0; i < 8; ++i) {
            float v = (col < 9) ? Wout[(k0 + i) * 9 + col] : 0.f;
            unsigned short h = f2bf(v);
            r[i] = pl ? f2bf(v - bf2f(h)) : h;
          }
          wo[ks][pl] = r;
        }
      }
  }
  __syncthreads();
  if (w < 6) {
    f32x4 oc = f32x4{0.f, 0.f, 0.f, 0.f};
#pragma unroll
    for (int ks = 0; ks < 4; ++ks) {
      int node = w * 16 + rsel;
      int ba = (ks * 4 + kh) * 1536 + node * 16;
      u16x8 hh = *(const u16x8*)(lds + HB + ba);
      u16x8 hl = *(const u16x8*)(lds + HB + 24576 + ba);
      oc = mfma16(hh, wo[ks][0], oc);
      oc = mfma16(hh, wo[ks][1], oc);
      oc = mfma16(hl, wo[ks][0], oc);
    }
    int colo = rsel;
    if (colo < 9) {
      float bo = bout[colo];
#pragma unroll
      for (int r = 0; r < 4; ++r) {
        int node = w * 16 + kh * 4 + r;
        if (node < 81) out[b * 729 + node * 9 + colo] = oc[r] + bo;
      }
    }
  }
}

// ------------------------------- launcher ------------------------------------
extern "C" void kernel_launch(void* const* d_in, const int* in_sizes, int n_in,
                              void* d_out, int out_size, void* d_ws, size_t ws_size,
                              hipStream_t stream) {
  const int*   x    = (const int*)d_in[0];
  const float* Win  = (const float*)d_in[1];
  const float* bin  = (const float*)d_in[2];
  const float* Wl   = (const float*)d_in[3];
  const float* blay = (const float*)d_in[4];
  const float* Wout = (const float*)d_in[5];
  const float* bout = (const float*)d_in[6];
  float* out = (float*)d_out;
  int nB = in_sizes[0] / 81;

  bool pre = ws_size >= WS_NEED;
  gnn_setup<<<1, 256, 0, stream>>>(Win, bin, Wl, (float*)d_ws);     // U -> ws+0
  if (pre)
    gnn_pack<<<362, 64, 0, stream>>>(Wl, Wout, (const float*)d_ws, (char*)d_ws);

  if (pre) {
    hipFuncSetAttribute((const void*)gnn_main<true>,
                        hipFuncAttributeMaxDynamicSharedMemorySize, LDS_SZ);
    gnn_main<true><<<nB, 768, LDS_SZ, stream>>>(x, Wl, blay, Wout, bout,
                                                (const float*)d_ws, out, nB);
  } else {
    hipFuncSetAttribute((const void*)gnn_main<false>,
                        hipFuncAttributeMaxDynamicSharedMemorySize, LDS_SZ);
    gnn_main<false><<<nB, 768, LDS_SZ, stream>>>(x, Wl, blay, Wout, bout,
                                                 (const float*)d_ws, out, nB);
  }
}

// Round 9
// 493.040 us; speedup vs baseline: 1.3468x; 1.3468x over previous
//
#include <hip/hip_runtime.h>
#include <hip/hip_bf16.h>

// ---------------------------------------------------------------------------
// Sudoku GCN, fully fused, MFMA-everything.
//   h_{l+1} = relu( (A+I) h_l * (W_l/21) + b_l ),  A+I exact 0/1 in bf16.
// Orientation ping-pong (no transposed reads, all epi writes b64-packed):
//   hbuf = h^T [feat][node] (chunk-major); agg: g^T = h^T (A+I);
//   gemm: h' = g (W/21); l=6: h6^T = W^T g^T -> h6 [node][feat] for out-GEMM.
// Layer 1 collapsed: h1 = relu(Cnt @ U + b1), U = relu(Win+bin)@W1/21.
// R9: latency/barrier fix (R8 proved we're NOT LDS-throughput-bound: 1.9x
// fewer LDS bytes, same time, occupancy down = slower). Get 2 INDEPENDENT
// blocks/CU so barrier+latency gaps overlap: gbuf (48K) replaced by a 24K
// 64-feat g-SLICE (agg slice -> bar -> K-accumulate slice, x2 per layer).
// LDS 78.4K -> 2 blocks/CU. 512 thr / 8 waves, 3n x 2f tiles per wave,
// launch_bounds(512,4) = 128-reg cap (est peak ~110, wbf per-slice).
// gslice swizzle: byte(node,floc) = node*128 + (((floc>>3)+node)&7)*16
// + (floc&7)*2 -> 2-way banks on epi-writes and k-reads (free).
// ---------------------------------------------------------------------------

typedef short          s16x8 __attribute__((ext_vector_type(8)));
typedef unsigned short u16x8 __attribute__((ext_vector_type(8)));
typedef unsigned short u16x4 __attribute__((ext_vector_type(4)));
typedef float          f32x4 __attribute__((ext_vector_type(4)));

#define HB    0       // hbuf: [2 pl][12 nodechunk][128 feat][16B], plane 24576
#define GS    49152   // gslice: [2 pl][96 node][64 feat swizzled], plane 12288
#define GSLO  12288
#define CNT   73728   // cnt : [4 chunk][96 node][16B] = 6144
#define XC    79872   // x cache: 81 ints
#define LDS_SZ 80256  // x2 = 160512 <= 163840 -> 2 blocks/CU

#define OFF_WB   5120     // [l 0..4][nt 0..7][ks 0..3][pl 0..1] x 1024B
#define OFF_AB   332800   // [nt 0..5][ks 0..2] x 1024B  (A+I, hi only, exact)
#define OFF_UB   351232   // [nt 0..7][pl] x 1024B
#define OFF_WOUT 367616   // [ks 0..3][pl] x 1024B
#define WS_NEED  375808

__device__ __forceinline__ unsigned short f2bf(float f) {   // RTNE via v_cvt
  return __builtin_bit_cast(unsigned short, __float2bfloat16(f));
}
__device__ __forceinline__ float bf2f(unsigned short h) {
  unsigned u = ((unsigned)h) << 16;
  return __builtin_bit_cast(float, u);
}
__device__ __forceinline__ f32x4 mfma16(u16x8 a, u16x8 b, f32x4 c) {
  return __builtin_amdgcn_mfma_f32_16x16x32_bf16(
      __builtin_bit_cast(s16x8, a), __builtin_bit_cast(s16x8, b), c, 0, 0, 0);
}
__device__ __forceinline__ void split4(f32x4 v, u16x4& hi, u16x4& lo) {
#pragma unroll
  for (int r = 0; r < 4; ++r) {
    unsigned short h = f2bf(v[r]);
    hi[r] = h;
    lo[r] = f2bf(v[r] - bf2f(h));
  }
}
__device__ __forceinline__ bool adjf(int r, int c) {
  if (r >= 81 || c >= 81) return false;
  int ri = r / 9, rj = r % 9, ci = c / 9, cj = c % 9;
  return ri == ci || rj == cj || (ri / 3 == ci / 3 && rj / 3 == cj / 3);
}
__device__ __forceinline__ u16x8 makeAB(int nt, int ks, int lane) {
  int col = nt * 16 + (lane & 15), k0 = ks * 32 + (lane >> 4) * 8;
  u16x8 r;
#pragma unroll
  for (int i = 0; i < 8; ++i) r[i] = adjf(k0 + i, col) ? 0x3F80 : 0;
  return r;
}

// ---------------- setup1: U[10][128] = relu(Win+bin) @ W1 / 21 (f32, ws+0) ---
extern "C" __global__ void gnn_setup(const float* __restrict__ Win,
                                     const float* __restrict__ bin,
                                     const float* __restrict__ W1,
                                     float* __restrict__ U) {
  __shared__ float V[1280];
  int t = threadIdx.x;
#pragma unroll
  for (int q = 0; q < 5; ++q) {
    int idx = t + 256 * q;
    V[idx] = fmaxf(Win[idx] + bin[idx & 127], 0.f);
  }
  __syncthreads();
#pragma unroll
  for (int p = 0; p < 5; ++p) {
    int o = t + 256 * p;
    int d = o >> 7, c = o & 127;
    float s = 0.f;
    for (int f = 0; f < 128; ++f) s += V[d * 128 + f] * W1[f * 128 + c];
    U[o] = s * (1.f / 21.f);
  }
}

// ---------------- setup2: pack all B/A fragment blobs into ws ----------------
extern "C" __global__ void gnn_pack(const float* __restrict__ Wl,
                                    const float* __restrict__ Wout,
                                    const float* __restrict__ Uscr,
                                    char* __restrict__ G) {
  int unit = blockIdx.x, lane = threadIdx.x;
  int rsel = lane & 15, kh = lane >> 4;
  u16x8 r;
  char* dst;
  if (unit < 320) {                       // WB: ((l*8+nt)*4+ks)*2+pl
    int pl = unit & 1, ks = (unit >> 1) & 3, nt = (unit >> 3) & 7, l = unit >> 6;
    int col = nt * 16 + rsel, k0 = ks * 32 + kh * 8;
    const float* src = Wl + (l + 1) * 16384 + k0 * 128 + col;
#pragma unroll
    for (int i = 0; i < 8; ++i) {
      float v = src[i * 128] * (1.f / 21.f);
      unsigned short h = f2bf(v);
      r[i] = pl ? f2bf(v - bf2f(h)) : h;
    }
    dst = G + OFF_WB + unit * 1024 + lane * 16;
  } else if (unit < 338) {                // AB: nt*3+ks
    int u2 = unit - 320, nt = u2 / 3, ks = u2 % 3;
    r = makeAB(nt, ks, lane);
    dst = G + OFF_AB + u2 * 1024 + lane * 16;
  } else if (unit < 354) {                // UB: nt*2+pl
    int u2 = unit - 338, nt = u2 >> 1, pl = u2 & 1;
    int col = nt * 16 + rsel;
#pragma unroll
    for (int i = 0; i < 8; ++i) {
      int k = kh * 8 + i;
      float v = (k < 10) ? Uscr[k * 128 + col] : 0.f;
      unsigned short h = f2bf(v);
      r[i] = pl ? f2bf(v - bf2f(h)) : h;
    }
    dst = G + OFF_UB + u2 * 1024 + lane * 16;
  } else {                                // WOUT: ks*2+pl
    int u2 = unit - 354, ks = u2 >> 1, pl = u2 & 1;
    int col = rsel, k0 = ks * 32 + kh * 8;
#pragma unroll
    for (int i = 0; i < 8; ++i) {
      float v = (col < 9) ? Wout[(k0 + i) * 9 + col] : 0.f;
      unsigned short h = f2bf(v);
      r[i] = pl ? f2bf(v - bf2f(h)) : h;
    }
    dst = G + OFF_WOUT + u2 * 1024 + lane * 16;
  }
  *(u16x8*)dst = r;
}

// --------------------------------- main -------------------------------------
template <bool PRE>
__global__ void __launch_bounds__(512, 4)
gnn_main(const int* __restrict__ x, const float* __restrict__ Wl,
         const float* __restrict__ bl, const float* __restrict__ Wout,
         const float* __restrict__ bout, const float* __restrict__ ws,
         float* __restrict__ out, int nB) {
  extern __shared__ char lds[];
  const int t = threadIdx.x, lane = t & 63, w = t >> 6;   // w 0..7
  const int rsel = lane & 15, kh = lane >> 4;
  const char* G = (const char*)ws;
  const int b = blockIdx.x;

  const int ng = w & 1;                  // node triple: ntiles ng*3+{0,1,2}
  const int fg = w >> 1;                 // 0..3: out ftiles fg*2+{0,1};
                                         // agg ftile (per slice s) = s*4+fg

  // ---- persistent A+I B-frags (exact, hi only): 3 ntiles x 3 ks = 36 VGPR --
  u16x8 abf[3][3];
#pragma unroll
  for (int j = 0; j < 3; ++j)
#pragma unroll
    for (int ks = 0; ks < 3; ++ks) {
      if constexpr (PRE)
        abf[j][ks] = *(const u16x8*)(G + OFF_AB + (((ng * 3 + j) * 3 + ks) << 10) + lane * 16);
      else
        abf[j][ks] = makeAB(ng * 3 + j, ks, lane);
    }

  // per-slice W frags: [kk][jf][pl] = 8 frags = 32 VGPR
  u16x8 wbf[2][2][2];
  auto loadWBslice = [&](int blob, int s) {
#pragma unroll
    for (int kk = 0; kk < 2; ++kk)
#pragma unroll
      for (int jf = 0; jf < 2; ++jf)
#pragma unroll
        for (int pl = 0; pl < 2; ++pl) {
          if constexpr (PRE) {
            wbf[kk][jf][pl] = *(const u16x8*)(
                G + OFF_WB +
                ((((blob * 8 + (fg * 2 + jf)) * 4 + (s * 2 + kk)) * 2 + pl) << 10) +
                lane * 16);
          } else {
            int colw = (fg * 2 + jf) * 16 + rsel, k0 = (s * 2 + kk) * 32 + kh * 8;
            const float* src = Wl + (blob + 1) * 16384 + k0 * 128 + colw;
            u16x8 r;
#pragma unroll
            for (int i = 0; i < 8; ++i) {
              float v = src[i * 128] * (1.f / 21.f);
              unsigned short h = f2bf(v);
              r[i] = pl ? f2bf(v - bf2f(h)) : h;
            }
            wbf[kk][jf][pl] = r;
          }
        }
  };

  // ---- x cache + digit counts -> cntbuf ----
  if (t < 81) ((int*)(lds + XC))[t] = x[b * 81 + t];
  __syncthreads();
  if (t < 96) {
    unsigned short cnt[16];
#pragma unroll
    for (int d = 0; d < 16; ++d) cnt[d] = 0;
    if (t < 81) {
      const int* xs = (const int*)(lds + XC);
      int n = t, i = n / 9, j = n - 9 * i;
      int bi = (i / 3) * 3, bj = (j / 3) * 3;
      int rv[9], cv[9], bv[9], rb3[3], cb3[3];
#pragma unroll
      for (int k = 0; k < 9; ++k) rv[k] = xs[i * 9 + k];
#pragma unroll
      for (int k = 0; k < 9; ++k) cv[k] = xs[k * 9 + j];
#pragma unroll
      for (int r2 = 0; r2 < 3; ++r2)
#pragma unroll
        for (int c2 = 0; c2 < 3; ++c2) bv[r2 * 3 + c2] = xs[(bi + r2) * 9 + (bj + c2)];
#pragma unroll
      for (int k = 0; k < 3; ++k) rb3[k] = xs[i * 9 + bj + k];
#pragma unroll
      for (int k = 0; k < 3; ++k) cb3[k] = xs[(bi + k) * 9 + j];
#pragma unroll
      for (int d = 0; d < 10; ++d) {
        int c = 0;
#pragma unroll
        for (int k = 0; k < 9; ++k) c += (rv[k] == d) + (cv[k] == d) + (bv[k] == d);
#pragma unroll
        for (int k = 0; k < 3; ++k) c -= (rb3[k] == d) + (cb3[k] == d);
        cnt[d] = f2bf((float)c);         // integers <=21: exact in bf16
      }
    }
    u16x8 c0, c1, z;
#pragma unroll
    for (int e = 0; e < 8; ++e) { c0[e] = cnt[e]; c1[e] = cnt[8 + e]; z[e] = 0; }
    *(u16x8*)(lds + CNT + 0 * 1536 + t * 16) = c0;
    *(u16x8*)(lds + CNT + 1 * 1536 + t * 16) = c1;
    *(u16x8*)(lds + CNT + 2 * 1536 + t * 16) = z;
    *(u16x8*)(lds + CNT + 3 * 1536 + t * 16) = z;
  }
  __syncthreads();

  // ---- L1 GEMM: h1 = relu(Cnt @ U + b1) -> hbuf [feat][node] (3x2 tiles) ---
  {
    u16x8 ubf[2][2];                     // [jf][pl], dead after L1
#pragma unroll
    for (int jf = 0; jf < 2; ++jf)
#pragma unroll
      for (int pl = 0; pl < 2; ++pl) {
        if constexpr (PRE)
          ubf[jf][pl] = *(const u16x8*)(G + OFF_UB + (((fg * 2 + jf) * 2 + pl) << 10) + lane * 16);
        else {
          int col = (fg * 2 + jf) * 16 + rsel;
          u16x8 r;
#pragma unroll
          for (int i = 0; i < 8; ++i) {
            int k = kh * 8 + i;
            float v = (k < 10) ? ws[k * 128 + col] : 0.f;
            unsigned short h = f2bf(v);
            r[i] = pl ? f2bf(v - bf2f(h)) : h;
          }
          ubf[jf][pl] = r;
        }
      }
    float bL1[2];
#pragma unroll
    for (int jf = 0; jf < 2; ++jf) bL1[jf] = bl[(fg * 2 + jf) * 16 + rsel];

    f32x4 a1[3][2];
#pragma unroll
    for (int jn = 0; jn < 3; ++jn)
#pragma unroll
      for (int jf = 0; jf < 2; ++jf) a1[jn][jf] = f32x4{0.f, 0.f, 0.f, 0.f};
#pragma unroll
    for (int jn = 0; jn < 3; ++jn) {
      int node = (ng * 3 + jn) * 16 + rsel;
      u16x8 af = *(const u16x8*)(lds + CNT + kh * 1536 + node * 16);
#pragma unroll
      for (int jf = 0; jf < 2; ++jf) {
        a1[jn][jf] = mfma16(af, ubf[jf][0], a1[jn][jf]);
        a1[jn][jf] = mfma16(af, ubf[jf][1], a1[jn][jf]);
      }
    }
#pragma unroll
    for (int jn = 0; jn < 3; ++jn)
#pragma unroll
      for (int jf = 0; jf < 2; ++jf) {
        int node0 = (ng * 3 + jn) * 16 + kh * 4;
        int feat = (fg * 2 + jf) * 16 + rsel;
        f32x4 v;
#pragma unroll
        for (int r = 0; r < 4; ++r) {
          float u = fmaxf(a1[jn][jf][r] + bL1[jf], 0.f);
          v[r] = (node0 + r < 81) ? u : 0.f;
        }
        u16x4 hi, lo;
        split4(v, hi, lo);
        int base = (node0 >> 3) * 2048 + feat * 16 + (node0 & 7) * 2;
        *(u16x4*)(lds + HB + base) = hi;
        *(u16x4*)(lds + HB + 24576 + base) = lo;
      }
  }

  // agg of one 64-feat slice: g^T tile (ftile s*4+fg, ntiles ng*3+{0..2})
  auto do_agg_slice = [&](int s) {
    f32x4 ag[3];
#pragma unroll
    for (int j = 0; j < 3; ++j) ag[j] = f32x4{0.f, 0.f, 0.f, 0.f};
    int feat = (s * 4 + fg) * 16 + rsel;
#pragma unroll
    for (int ks = 0; ks < 3; ++ks) {
      int ba = (ks * 4 + kh) * 2048 + feat * 16;
      u16x8 ah = *(const u16x8*)(lds + HB + ba);
      u16x8 al = *(const u16x8*)(lds + HB + 24576 + ba);
#pragma unroll
      for (int j = 0; j < 3; ++j) {
        ag[j] = mfma16(ah, abf[j][ks], ag[j]);
        ag[j] = mfma16(al, abf[j][ks], ag[j]);
      }
    }
    // epi -> gslice, swizzled; no bias/relu/mask (cols>=81 are already 0)
    int wbase = fg * 16 + kh * 4;        // within-slice floc base
    int wfb = wbase >> 3, woff = (wbase & 7) * 2;
#pragma unroll
    for (int j = 0; j < 3; ++j) {
      int node = (ng * 3 + j) * 16 + rsel;
      u16x4 hi, lo;
      split4(ag[j], hi, lo);
      int ad = node * 128 + (((wfb + node) & 7) << 4) + woff;
      *(u16x4*)(lds + GS + ad) = hi;
      *(u16x4*)(lds + GS + GSLO + ad) = lo;
    }
  };

  // ---- GCN layers 2..5 (l=1..4): per layer 2 slices of K=64 ----
  f32x4 wc[3][2];
#pragma unroll 1
  for (int l = 1; l <= 4; ++l) {
    __syncthreads();                     // HB ready (prev epi)
    float bw[2];
#pragma unroll
    for (int jf = 0; jf < 2; ++jf) bw[jf] = bl[l * 128 + (fg * 2 + jf) * 16 + rsel];
#pragma unroll
    for (int jm = 0; jm < 3; ++jm)
#pragma unroll
      for (int jf = 0; jf < 2; ++jf) wc[jm][jf] = f32x4{0.f, 0.f, 0.f, 0.f};
#pragma unroll
    for (int s = 0; s < 2; ++s) {
      do_agg_slice(s);
      loadWBslice(l - 1, s);             // latency hides under bar + other block
      __syncthreads();                   // GS ready
#pragma unroll
      for (int kk = 0; kk < 2; ++kk) {
#pragma unroll
        for (int jm = 0; jm < 3; ++jm) {
          int node = (ng * 3 + jm) * 16 + rsel;
          int ad = node * 128 + (((4 * kk + kh + node) & 7) << 4);
          u16x8 gh = *(const u16x8*)(lds + GS + ad);
          u16x8 gl = *(const u16x8*)(lds + GS + GSLO + ad);
#pragma unroll
          for (int jf = 0; jf < 2; ++jf) {
            wc[jm][jf] = mfma16(gh, wbf[kk][jf][0], wc[jm][jf]);
            wc[jm][jf] = mfma16(gh, wbf[kk][jf][1], wc[jm][jf]);
            wc[jm][jf] = mfma16(gl, wbf[kk][jf][0], wc[jm][jf]);
          }
        }
      }
      if (s == 0) __syncthreads();       // GS consumed before slice-1 agg
    }
    // epi: bias+relu+mask -> hbuf [feat][node]  (all HB readers done)
#pragma unroll
    for (int jm = 0; jm < 3; ++jm)
#pragma unroll
      for (int jf = 0; jf < 2; ++jf) {
        int node0 = (ng * 3 + jm) * 16 + kh * 4;
        int feat = (fg * 2 + jf) * 16 + rsel;
        f32x4 v;
#pragma unroll
        for (int r = 0; r < 4; ++r) {
          float u = fmaxf(wc[jm][jf][r] + bw[jf], 0.f);
          v[r] = (node0 + r < 81) ? u : 0.f;
        }
        u16x4 hi, lo;
        split4(v, hi, lo);
        int base = (node0 >> 3) * 2048 + feat * 16 + (node0 & 7) * 2;
        *(u16x4*)(lds + HB + base) = hi;
        *(u16x4*)(lds + HB + 24576 + base) = lo;
      }
  }

  // ---- layer 6 (l=5), flipped: h6^T = (W/21)^T g^T, sliced the same way ----
  __syncthreads();                       // HB (h5) ready
  {
    float b5[2][4];
#pragma unroll
    for (int jf = 0; jf < 2; ++jf)
#pragma unroll
      for (int r = 0; r < 4; ++r)
        b5[jf][r] = bl[5 * 128 + (fg * 2 + jf) * 16 + kh * 4 + r];
    f32x4 w6[2][3];
#pragma unroll
    for (int jf = 0; jf < 2; ++jf)
#pragma unroll
      for (int jn = 0; jn < 3; ++jn) w6[jf][jn] = f32x4{0.f, 0.f, 0.f, 0.f};
#pragma unroll
    for (int s = 0; s < 2; ++s) {
      do_agg_slice(s);
      loadWBslice(4, s);
      __syncthreads();                   // GS ready
#pragma unroll
      for (int kk = 0; kk < 2; ++kk) {
#pragma unroll
        for (int jn = 0; jn < 3; ++jn) {
          int node = (ng * 3 + jn) * 16 + rsel;
          int ad = node * 128 + (((4 * kk + kh + node) & 7) << 4);
          u16x8 gh = *(const u16x8*)(lds + GS + ad);
          u16x8 gl = *(const u16x8*)(lds + GS + GSLO + ad);
#pragma unroll
          for (int jf = 0; jf < 2; ++jf) {
            w6[jf][jn] = mfma16(wbf[kk][jf][0], gh, w6[jf][jn]);
            w6[jf][jn] = mfma16(wbf[kk][jf][0], gl, w6[jf][jn]);
            w6[jf][jn] = mfma16(wbf[kk][jf][1], gh, w6[jf][jn]);
          }
        }
      }
      if (s == 0) __syncthreads();
    }
    // epi: C row=feat_out(4 consec), col=node -> h6 [node][feat] into HB
#pragma unroll
    for (int jf = 0; jf < 2; ++jf)
#pragma unroll
      for (int jn = 0; jn < 3; ++jn) {
        int node = (ng * 3 + jn) * 16 + rsel;
        int f0 = (fg * 2 + jf) * 16 + kh * 4;
        f32x4 v;
#pragma unroll
        for (int r = 0; r < 4; ++r) {
          float u = fmaxf(w6[jf][jn][r] + b5[jf][r], 0.f);
          v[r] = (node < 81) ? u : 0.f;
        }
        u16x4 hi, lo;
        split4(v, hi, lo);
        int base = (f0 >> 3) * 1536 + node * 16 + (f0 & 7) * 2;
        *(u16x4*)(lds + HB + base) = hi;
        *(u16x4*)(lds + HB + 24576 + base) = lo;
      }
  }

  // ---- output GEMM: logits = h6 @ Wout + bout (waves 0..5, 1 tile each) ----
  u16x8 wo[4][2];
  if (w < 6) {
#pragma unroll
    for (int ks = 0; ks < 4; ++ks)
#pragma unroll
      for (int pl = 0; pl < 2; ++pl) {
        if constexpr (PRE)
          wo[ks][pl] = *(const u16x8*)(G + OFF_WOUT + (ks * 2 + pl) * 1024 + lane * 16);
        else {
          int col = rsel, k0 = ks * 32 + kh * 8;
          u16x8 r;
#pragma unroll
          for (int i = 0; i < 8; ++i) {
            float v = (col < 9) ? Wout[(k0 + i) * 9 + col] : 0.f;
            unsigned short h = f2bf(v);
            r[i] = pl ? f2bf(v - bf2f(h)) : h;
          }
          wo[ks][pl] = r;
        }
      }
  }
  __syncthreads();
  if (w < 6) {
    f32x4 oc = f32x4{0.f, 0.f, 0.f, 0.f};
#pragma unroll
    for (int ks = 0; ks < 4; ++ks) {
      int node = w * 16 + rsel;
      int ba = (ks * 4 + kh) * 1536 + node * 16;
      u16x8 hh = *(const u16x8*)(lds + HB + ba);
      u16x8 hl = *(const u16x8*)(lds + HB + 24576 + ba);
      oc = mfma16(hh, wo[ks][0], oc);
      oc = mfma16(hh, wo[ks][1], oc);
      oc = mfma16(hl, wo[ks][0], oc);
    }
    int colo = rsel;
    if (colo < 9) {
      float bo = bout[colo];
#pragma unroll
      for (int r = 0; r < 4; ++r) {
        int node = w * 16 + kh * 4 + r;
        if (node < 81) out[b * 729 + node * 9 + colo] = oc[r] + bo;
      }
    }
  }
}

// ------------------------------- launcher ------------------------------------
extern "C" void kernel_launch(void* const* d_in, const int* in_sizes, int n_in,
                              void* d_out, int out_size, void* d_ws, size_t ws_size,
                              hipStream_t stream) {
  const int*   x    = (const int*)d_in[0];
  const float* Win  = (const float*)d_in[1];
  const float* bin  = (const float*)d_in[2];
  const float* Wl   = (const float*)d_in[3];
  const float* blay = (const float*)d_in[4];
  const float* Wout = (const float*)d_in[5];
  const float* bout = (const float*)d_in[6];
  float* out = (float*)d_out;
  int nB = in_sizes[0] / 81;

  bool pre = ws_size >= WS_NEED;
  gnn_setup<<<1, 256, 0, stream>>>(Win, bin, Wl, (float*)d_ws);     // U -> ws+0
  if (pre)
    gnn_pack<<<362, 64, 0, stream>>>(Wl, Wout, (const float*)d_ws, (char*)d_ws);

  if (pre) {
    hipFuncSetAttribute((const void*)gnn_main<true>,
                        hipFuncAttributeMaxDynamicSharedMemorySize, LDS_SZ);
    gnn_main<true><<<nB, 512, LDS_SZ, stream>>>(x, Wl, blay, Wout, bout,
                                                (const float*)d_ws, out, nB);
  } else {
    hipFuncSetAttribute((const void*)gnn_main<false>,
                        hipFuncAttributeMaxDynamicSharedMemorySize, LDS_SZ);
    gnn_main<false><<<nB, 512, LDS_SZ, stream>>>(x, Wl, blay, Wout, bout,
                                                 (const float*)d_ws, out, nB);
  }
}

// Round 10
// 473.036 us; speedup vs baseline: 1.4037x; 1.0423x over previous
//
#include <hip/hip_runtime.h>
#include <hip/hip_bf16.h>

// ---------------------------------------------------------------------------
// Sudoku GCN, fully fused, MFMA-everything.
//   h_{l+1} = relu( (A+I) h_l * (W_l/21) + b_l ),  A+I exact 0/1 in bf16.
// Orientation ping-pong (no transposed reads, all epi writes b64-packed):
//   hbuf = h^T [feat][node] (chunk-major); agg: g^T = h^T (A+I);
//   gemm: h' = g (W/21); l=6: h6^T = W^T g^T -> h6 [node][feat] for out-GEMM.
// Layer 1 collapsed: h1 = relu(Cnt @ U + b1), U = relu(Win+bin)@W1/21.
// R9: 64-feat g-slices -> LDS 78.4K -> 2 independent blocks/CU (barrier
// overlap across blocks). R10: kill the returned spill (R9: 219 MB scratch
// writes, demand ~140 > 128-reg cap of 4 waves/SIMD). W frags now per-k-chunk
// (4 frags = 16 VGPR, was 32): kk0 loaded before the GS barrier (hides under
// agg), kk1 loaded after kk0's MFMAs into the SAME regs (sequential WAR ->
// reuse; latency covered by 16 co-resident waves). Peak ~110 < 128.
// ---------------------------------------------------------------------------

typedef short          s16x8 __attribute__((ext_vector_type(8)));
typedef unsigned short u16x8 __attribute__((ext_vector_type(8)));
typedef unsigned short u16x4 __attribute__((ext_vector_type(4)));
typedef float          f32x4 __attribute__((ext_vector_type(4)));

#define HB    0       // hbuf: [2 pl][12 nodechunk][128 feat][16B], plane 24576
#define GS    49152   // gslice: [2 pl][96 node][64 feat swizzled], plane 12288
#define GSLO  12288
#define CNT   73728   // cnt : [4 chunk][96 node][16B] = 6144
#define XC    79872   // x cache: 81 ints
#define LDS_SZ 80256  // x2 = 160512 <= 163840 -> 2 blocks/CU

#define OFF_WB   5120     // [l 0..4][nt 0..7][ks 0..3][pl 0..1] x 1024B
#define OFF_AB   332800   // [nt 0..5][ks 0..2] x 1024B  (A+I, hi only, exact)
#define OFF_UB   351232   // [nt 0..7][pl] x 1024B
#define OFF_WOUT 367616   // [ks 0..3][pl] x 1024B
#define WS_NEED  375808

__device__ __forceinline__ unsigned short f2bf(float f) {   // RTNE via v_cvt
  return __builtin_bit_cast(unsigned short, __float2bfloat16(f));
}
__device__ __forceinline__ float bf2f(unsigned short h) {
  unsigned u = ((unsigned)h) << 16;
  return __builtin_bit_cast(float, u);
}
__device__ __forceinline__ f32x4 mfma16(u16x8 a, u16x8 b, f32x4 c) {
  return __builtin_amdgcn_mfma_f32_16x16x32_bf16(
      __builtin_bit_cast(s16x8, a), __builtin_bit_cast(s16x8, b), c, 0, 0, 0);
}
__device__ __forceinline__ void split4(f32x4 v, u16x4& hi, u16x4& lo) {
#pragma unroll
  for (int r = 0; r < 4; ++r) {
    unsigned short h = f2bf(v[r]);
    hi[r] = h;
    lo[r] = f2bf(v[r] - bf2f(h));
  }
}
__device__ __forceinline__ bool adjf(int r, int c) {
  if (r >= 81 || c >= 81) return false;
  int ri = r / 9, rj = r % 9, ci = c / 9, cj = c % 9;
  return ri == ci || rj == cj || (ri / 3 == ci / 3 && rj / 3 == cj / 3);
}
__device__ __forceinline__ u16x8 makeAB(int nt, int ks, int lane) {
  int col = nt * 16 + (lane & 15), k0 = ks * 32 + (lane >> 4) * 8;
  u16x8 r;
#pragma unroll
  for (int i = 0; i < 8; ++i) r[i] = adjf(k0 + i, col) ? 0x3F80 : 0;
  return r;
}

// ---------------- setup1: U[10][128] = relu(Win+bin) @ W1 / 21 (f32, ws+0) ---
extern "C" __global__ void gnn_setup(const float* __restrict__ Win,
                                     const float* __restrict__ bin,
                                     const float* __restrict__ W1,
                                     float* __restrict__ U) {
  __shared__ float V[1280];
  int t = threadIdx.x;
#pragma unroll
  for (int q = 0; q < 5; ++q) {
    int idx = t + 256 * q;
    V[idx] = fmaxf(Win[idx] + bin[idx & 127], 0.f);
  }
  __syncthreads();
#pragma unroll
  for (int p = 0; p < 5; ++p) {
    int o = t + 256 * p;
    int d = o >> 7, c = o & 127;
    float s = 0.f;
    for (int f = 0; f < 128; ++f) s += V[d * 128 + f] * W1[f * 128 + c];
    U[o] = s * (1.f / 21.f);
  }
}

// ---------------- setup2: pack all B/A fragment blobs into ws ----------------
extern "C" __global__ void gnn_pack(const float* __restrict__ Wl,
                                    const float* __restrict__ Wout,
                                    const float* __restrict__ Uscr,
                                    char* __restrict__ G) {
  int unit = blockIdx.x, lane = threadIdx.x;
  int rsel = lane & 15, kh = lane >> 4;
  u16x8 r;
  char* dst;
  if (unit < 320) {                       // WB: ((l*8+nt)*4+ks)*2+pl
    int pl = unit & 1, ks = (unit >> 1) & 3, nt = (unit >> 3) & 7, l = unit >> 6;
    int col = nt * 16 + rsel, k0 = ks * 32 + kh * 8;
    const float* src = Wl + (l + 1) * 16384 + k0 * 128 + col;
#pragma unroll
    for (int i = 0; i < 8; ++i) {
      float v = src[i * 128] * (1.f / 21.f);
      unsigned short h = f2bf(v);
      r[i] = pl ? f2bf(v - bf2f(h)) : h;
    }
    dst = G + OFF_WB + unit * 1024 + lane * 16;
  } else if (unit < 338) {                // AB: nt*3+ks
    int u2 = unit - 320, nt = u2 / 3, ks = u2 % 3;
    r = makeAB(nt, ks, lane);
    dst = G + OFF_AB + u2 * 1024 + lane * 16;
  } else if (unit < 354) {                // UB: nt*2+pl
    int u2 = unit - 338, nt = u2 >> 1, pl = u2 & 1;
    int col = nt * 16 + rsel;
#pragma unroll
    for (int i = 0; i < 8; ++i) {
      int k = kh * 8 + i;
      float v = (k < 10) ? Uscr[k * 128 + col] : 0.f;
      unsigned short h = f2bf(v);
      r[i] = pl ? f2bf(v - bf2f(h)) : h;
    }
    dst = G + OFF_UB + u2 * 1024 + lane * 16;
  } else {                                // WOUT: ks*2+pl
    int u2 = unit - 354, ks = u2 >> 1, pl = u2 & 1;
    int col = rsel, k0 = ks * 32 + kh * 8;
#pragma unroll
    for (int i = 0; i < 8; ++i) {
      float v = (col < 9) ? Wout[(k0 + i) * 9 + col] : 0.f;
      unsigned short h = f2bf(v);
      r[i] = pl ? f2bf(v - bf2f(h)) : h;
    }
    dst = G + OFF_WOUT + u2 * 1024 + lane * 16;
  }
  *(u16x8*)dst = r;
}

// --------------------------------- main -------------------------------------
template <bool PRE>
__global__ void __launch_bounds__(512, 4)
gnn_main(const int* __restrict__ x, const float* __restrict__ Wl,
         const float* __restrict__ bl, const float* __restrict__ Wout,
         const float* __restrict__ bout, const float* __restrict__ ws,
         float* __restrict__ out, int nB) {
  extern __shared__ char lds[];
  const int t = threadIdx.x, lane = t & 63, w = t >> 6;   // w 0..7
  const int rsel = lane & 15, kh = lane >> 4;
  const char* G = (const char*)ws;
  const int b = blockIdx.x;

  const int ng = w & 1;                  // node triple: ntiles ng*3+{0,1,2}
  const int fg = w >> 1;                 // 0..3: out ftiles fg*2+{0,1};
                                         // agg ftile (per slice s) = s*4+fg

  // ---- persistent A+I B-frags (exact, hi only): 3 ntiles x 3 ks = 36 VGPR --
  u16x8 abf[3][3];
#pragma unroll
  for (int j = 0; j < 3; ++j)
#pragma unroll
    for (int ks = 0; ks < 3; ++ks) {
      if constexpr (PRE)
        abf[j][ks] = *(const u16x8*)(G + OFF_AB + (((ng * 3 + j) * 3 + ks) << 10) + lane * 16);
      else
        abf[j][ks] = makeAB(ng * 3 + j, ks, lane);
    }

  // per-k-chunk W frags: [jf][pl] = 4 frags = 16 VGPR (R10: was per-slice 32)
  u16x8 wb[2][2];
  auto loadWBkk = [&](int blob, int s, int kk) {
#pragma unroll
    for (int jf = 0; jf < 2; ++jf)
#pragma unroll
      for (int pl = 0; pl < 2; ++pl) {
        if constexpr (PRE) {
          wb[jf][pl] = *(const u16x8*)(
              G + OFF_WB +
              ((((blob * 8 + (fg * 2 + jf)) * 4 + (s * 2 + kk)) * 2 + pl) << 10) +
              lane * 16);
        } else {
          int colw = (fg * 2 + jf) * 16 + rsel, k0 = (s * 2 + kk) * 32 + kh * 8;
          const float* src = Wl + (blob + 1) * 16384 + k0 * 128 + colw;
          u16x8 r;
#pragma unroll
          for (int i = 0; i < 8; ++i) {
            float v = src[i * 128] * (1.f / 21.f);
            unsigned short h = f2bf(v);
            r[i] = pl ? f2bf(v - bf2f(h)) : h;
          }
          wb[jf][pl] = r;
        }
      }
  };

  // ---- x cache + digit counts -> cntbuf ----
  if (t < 81) ((int*)(lds + XC))[t] = x[b * 81 + t];
  __syncthreads();
  if (t < 96) {
    unsigned short cnt[16];
#pragma unroll
    for (int d = 0; d < 16; ++d) cnt[d] = 0;
    if (t < 81) {
      const int* xs = (const int*)(lds + XC);
      int n = t, i = n / 9, j = n - 9 * i;
      int bi = (i / 3) * 3, bj = (j / 3) * 3;
      int rv[9], cv[9], bv[9], rb3[3], cb3[3];
#pragma unroll
      for (int k = 0; k < 9; ++k) rv[k] = xs[i * 9 + k];
#pragma unroll
      for (int k = 0; k < 9; ++k) cv[k] = xs[k * 9 + j];
#pragma unroll
      for (int r2 = 0; r2 < 3; ++r2)
#pragma unroll
        for (int c2 = 0; c2 < 3; ++c2) bv[r2 * 3 + c2] = xs[(bi + r2) * 9 + (bj + c2)];
#pragma unroll
      for (int k = 0; k < 3; ++k) rb3[k] = xs[i * 9 + bj + k];
#pragma unroll
      for (int k = 0; k < 3; ++k) cb3[k] = xs[(bi + k) * 9 + j];
#pragma unroll
      for (int d = 0; d < 10; ++d) {
        int c = 0;
#pragma unroll
        for (int k = 0; k < 9; ++k) c += (rv[k] == d) + (cv[k] == d) + (bv[k] == d);
#pragma unroll
        for (int k = 0; k < 3; ++k) c -= (rb3[k] == d) + (cb3[k] == d);
        cnt[d] = f2bf((float)c);         // integers <=21: exact in bf16
      }
    }
    u16x8 c0, c1, z;
#pragma unroll
    for (int e = 0; e < 8; ++e) { c0[e] = cnt[e]; c1[e] = cnt[8 + e]; z[e] = 0; }
    *(u16x8*)(lds + CNT + 0 * 1536 + t * 16) = c0;
    *(u16x8*)(lds + CNT + 1 * 1536 + t * 16) = c1;
    *(u16x8*)(lds + CNT + 2 * 1536 + t * 16) = z;
    *(u16x8*)(lds + CNT + 3 * 1536 + t * 16) = z;
  }
  __syncthreads();

  // ---- L1 GEMM: h1 = relu(Cnt @ U + b1) -> hbuf [feat][node] (3x2 tiles) ---
  {
    u16x8 ubf[2][2];                     // [jf][pl], dead after L1
#pragma unroll
    for (int jf = 0; jf < 2; ++jf)
#pragma unroll
      for (int pl = 0; pl < 2; ++pl) {
        if constexpr (PRE)
          ubf[jf][pl] = *(const u16x8*)(G + OFF_UB + (((fg * 2 + jf) * 2 + pl) << 10) + lane * 16);
        else {
          int col = (fg * 2 + jf) * 16 + rsel;
          u16x8 r;
#pragma unroll
          for (int i = 0; i < 8; ++i) {
            int k = kh * 8 + i;
            float v = (k < 10) ? ws[k * 128 + col] : 0.f;
            unsigned short h = f2bf(v);
            r[i] = pl ? f2bf(v - bf2f(h)) : h;
          }
          ubf[jf][pl] = r;
        }
      }
    float bL1[2];
#pragma unroll
    for (int jf = 0; jf < 2; ++jf) bL1[jf] = bl[(fg * 2 + jf) * 16 + rsel];

    f32x4 a1[3][2];
#pragma unroll
    for (int jn = 0; jn < 3; ++jn)
#pragma unroll
      for (int jf = 0; jf < 2; ++jf) a1[jn][jf] = f32x4{0.f, 0.f, 0.f, 0.f};
#pragma unroll
    for (int jn = 0; jn < 3; ++jn) {
      int node = (ng * 3 + jn) * 16 + rsel;
      u16x8 af = *(const u16x8*)(lds + CNT + kh * 1536 + node * 16);
#pragma unroll
      for (int jf = 0; jf < 2; ++jf) {
        a1[jn][jf] = mfma16(af, ubf[jf][0], a1[jn][jf]);
        a1[jn][jf] = mfma16(af, ubf[jf][1], a1[jn][jf]);
      }
    }
#pragma unroll
    for (int jn = 0; jn < 3; ++jn)
#pragma unroll
      for (int jf = 0; jf < 2; ++jf) {
        int node0 = (ng * 3 + jn) * 16 + kh * 4;
        int feat = (fg * 2 + jf) * 16 + rsel;
        f32x4 v;
#pragma unroll
        for (int r = 0; r < 4; ++r) {
          float u = fmaxf(a1[jn][jf][r] + bL1[jf], 0.f);
          v[r] = (node0 + r < 81) ? u : 0.f;
        }
        u16x4 hi, lo;
        split4(v, hi, lo);
        int base = (node0 >> 3) * 2048 + feat * 16 + (node0 & 7) * 2;
        *(u16x4*)(lds + HB + base) = hi;
        *(u16x4*)(lds + HB + 24576 + base) = lo;
      }
  }

  // agg of one 64-feat slice: g^T tile (ftile s*4+fg, ntiles ng*3+{0..2})
  auto do_agg_slice = [&](int s) {
    f32x4 ag[3];
#pragma unroll
    for (int j = 0; j < 3; ++j) ag[j] = f32x4{0.f, 0.f, 0.f, 0.f};
    int feat = (s * 4 + fg) * 16 + rsel;
#pragma unroll
    for (int ks = 0; ks < 3; ++ks) {
      int ba = (ks * 4 + kh) * 2048 + feat * 16;
      u16x8 ah = *(const u16x8*)(lds + HB + ba);
      u16x8 al = *(const u16x8*)(lds + HB + 24576 + ba);
#pragma unroll
      for (int j = 0; j < 3; ++j) {
        ag[j] = mfma16(ah, abf[j][ks], ag[j]);
        ag[j] = mfma16(al, abf[j][ks], ag[j]);
      }
    }
    // epi -> gslice, swizzled; no bias/relu/mask (cols>=81 are already 0)
    int wbase = fg * 16 + kh * 4;        // within-slice floc base
    int wfb = wbase >> 3, woff = (wbase & 7) * 2;
#pragma unroll
    for (int j = 0; j < 3; ++j) {
      int node = (ng * 3 + j) * 16 + rsel;
      u16x4 hi, lo;
      split4(ag[j], hi, lo);
      int ad = node * 128 + (((wfb + node) & 7) << 4) + woff;
      *(u16x4*)(lds + GS + ad) = hi;
      *(u16x4*)(lds + GS + GSLO + ad) = lo;
    }
  };

  // ---- GCN layers 2..5 (l=1..4): per layer 2 slices of K=64 ----
  f32x4 wc[3][2];
#pragma unroll 1
  for (int l = 1; l <= 4; ++l) {
    __syncthreads();                     // HB ready (prev epi)
    float bw[2];
#pragma unroll
    for (int jf = 0; jf < 2; ++jf) bw[jf] = bl[l * 128 + (fg * 2 + jf) * 16 + rsel];
#pragma unroll
    for (int jm = 0; jm < 3; ++jm)
#pragma unroll
      for (int jf = 0; jf < 2; ++jf) wc[jm][jf] = f32x4{0.f, 0.f, 0.f, 0.f};
#pragma unroll
    for (int s = 0; s < 2; ++s) {
      do_agg_slice(s);
      loadWBkk(l - 1, s, 0);             // kk0: hides under agg + barrier
      __syncthreads();                   // GS ready
#pragma unroll
      for (int kk = 0; kk < 2; ++kk) {
#pragma unroll
        for (int jm = 0; jm < 3; ++jm) {
          int node = (ng * 3 + jm) * 16 + rsel;
          int ad = node * 128 + (((4 * kk + kh + node) & 7) << 4);
          u16x8 gh = *(const u16x8*)(lds + GS + ad);
          u16x8 gl = *(const u16x8*)(lds + GS + GSLO + ad);
#pragma unroll
          for (int jf = 0; jf < 2; ++jf) {
            wc[jm][jf] = mfma16(gh, wb[jf][0], wc[jm][jf]);
            wc[jm][jf] = mfma16(gh, wb[jf][1], wc[jm][jf]);
            wc[jm][jf] = mfma16(gl, wb[jf][0], wc[jm][jf]);
          }
        }
        if (kk == 0) loadWBkk(l - 1, s, 1);   // reuse wb regs (WAR, sequential)
      }
      if (s == 0) __syncthreads();       // GS consumed before slice-1 agg
    }
    // epi: bias+relu+mask -> hbuf [feat][node]  (all HB readers done)
#pragma unroll
    for (int jm = 0; jm < 3; ++jm)
#pragma unroll
      for (int jf = 0; jf < 2; ++jf) {
        int node0 = (ng * 3 + jm) * 16 + kh * 4;
        int feat = (fg * 2 + jf) * 16 + rsel;
        f32x4 v;
#pragma unroll
        for (int r = 0; r < 4; ++r) {
          float u = fmaxf(wc[jm][jf][r] + bw[jf], 0.f);
          v[r] = (node0 + r < 81) ? u : 0.f;
        }
        u16x4 hi, lo;
        split4(v, hi, lo);
        int base = (node0 >> 3) * 2048 + feat * 16 + (node0 & 7) * 2;
        *(u16x4*)(lds + HB + base) = hi;
        *(u16x4*)(lds + HB + 24576 + base) = lo;
      }
  }

  // ---- layer 6 (l=5), flipped: h6^T = (W/21)^T g^T, sliced the same way ----
  __syncthreads();                       // HB (h5) ready
  {
    float b5[2][4];
#pragma unroll
    for (int jf = 0; jf < 2; ++jf)
#pragma unroll
      for (int r = 0; r < 4; ++r)
        b5[jf][r] = bl[5 * 128 + (fg * 2 + jf) * 16 + kh * 4 + r];
    f32x4 w6[2][3];
#pragma unroll
    for (int jf = 0; jf < 2; ++jf)
#pragma unroll
      for (int jn = 0; jn < 3; ++jn) w6[jf][jn] = f32x4{0.f, 0.f, 0.f, 0.f};
#pragma unroll
    for (int s = 0; s < 2; ++s) {
      do_agg_slice(s);
      loadWBkk(4, s, 0);
      __syncthreads();                   // GS ready
#pragma unroll
      for (int kk = 0; kk < 2; ++kk) {
#pragma unroll
        for (int jn = 0; jn < 3; ++jn) {
          int node = (ng * 3 + jn) * 16 + rsel;
          int ad = node * 128 + (((4 * kk + kh + node) & 7) << 4);
          u16x8 gh = *(const u16x8*)(lds + GS + ad);
          u16x8 gl = *(const u16x8*)(lds + GS + GSLO + ad);
#pragma unroll
          for (int jf = 0; jf < 2; ++jf) {
            w6[jf][jn] = mfma16(wb[jf][0], gh, w6[jf][jn]);
            w6[jf][jn] = mfma16(wb[jf][0], gl, w6[jf][jn]);
            w6[jf][jn] = mfma16(wb[jf][1], gh, w6[jf][jn]);
          }
        }
        if (kk == 0) loadWBkk(4, s, 1);
      }
      if (s == 0) __syncthreads();
    }
    // epi: C row=feat_out(4 consec), col=node -> h6 [node][feat] into HB
#pragma unroll
    for (int jf = 0; jf < 2; ++jf)
#pragma unroll
      for (int jn = 0; jn < 3; ++jn) {
        int node = (ng * 3 + jn) * 16 + rsel;
        int f0 = (fg * 2 + jf) * 16 + kh * 4;
        f32x4 v;
#pragma unroll
        for (int r = 0; r < 4; ++r) {
          float u = fmaxf(w6[jf][jn][r] + b5[jf][r], 0.f);
          v[r] = (node < 81) ? u : 0.f;
        }
        u16x4 hi, lo;
        split4(v, hi, lo);
        int base = (f0 >> 3) * 1536 + node * 16 + (f0 & 7) * 2;
        *(u16x4*)(lds + HB + base) = hi;
        *(u16x4*)(lds + HB + 24576 + base) = lo;
      }
  }

  // ---- output GEMM: logits = h6 @ Wout + bout (waves 0..5, 1 tile each) ----
  u16x8 wo[4][2];
  if (w < 6) {
#pragma unroll
    for (int ks = 0; ks < 4; ++ks)
#pragma unroll
      for (int pl = 0; pl < 2; ++pl) {
        if constexpr (PRE)
          wo[ks][pl] = *(const u16x8*)(G + OFF_WOUT + (ks * 2 + pl) * 1024 + lane * 16);
        else {
          int col = rsel, k0 = ks * 32 + kh * 8;
          u16x8 r;
#pragma unroll
          for (int i = 0; i < 8; ++i) {
            float v = (col < 9) ? Wout[(k0 + i) * 9 + col] : 0.f;
            unsigned short h = f2bf(v);
            r[i] = pl ? f2bf(v - bf2f(h)) : h;
          }
          wo[ks][pl] = r;
        }
      }
  }
  __syncthreads();
  if (w < 6) {
    f32x4 oc = f32x4{0.f, 0.f, 0.f, 0.f};
#pragma unroll
    for (int ks = 0; ks < 4; ++ks) {
      int node = w * 16 + rsel;
      int ba = (ks * 4 + kh) * 1536 + node * 16;
      u16x8 hh = *(const u16x8*)(lds + HB + ba);
      u16x8 hl = *(const u16x8*)(lds + HB + 24576 + ba);
      oc = mfma16(hh, wo[ks][0], oc);
      oc = mfma16(hh, wo[ks][1], oc);
      oc = mfma16(hl, wo[ks][0], oc);
    }
    int colo = rsel;
    if (colo < 9) {
      float bo = bout[colo];
#pragma unroll
      for (int r = 0; r < 4; ++r) {
        int node = w * 16 + kh * 4 + r;
        if (node < 81) out[b * 729 + node * 9 + colo] = oc[r] + bo;
      }
    }
  }
}

// ------------------------------- launcher ------------------------------------
extern "C" void kernel_launch(void* const* d_in, const int* in_sizes, int n_in,
                              void* d_out, int out_size, void* d_ws, size_t ws_size,
                              hipStream_t stream) {
  const int*   x    = (const int*)d_in[0];
  const float* Win  = (const float*)d_in[1];
  const float* bin  = (const float*)d_in[2];
  const float* Wl   = (const float*)d_in[3];
  const float* blay = (const float*)d_in[4];
  const float* Wout = (const float*)d_in[5];
  const float* bout = (const float*)d_in[6];
  float* out = (float*)d_out;
  int nB = in_sizes[0] / 81;

  bool pre = ws_size >= WS_NEED;
  gnn_setup<<<1, 256, 0, stream>>>(Win, bin, Wl, (float*)d_ws);     // U -> ws+0
  if (pre)
    gnn_pack<<<362, 64, 0, stream>>>(Wl, Wout, (const float*)d_ws, (char*)d_ws);

  if (pre) {
    hipFuncSetAttribute((const void*)gnn_main<true>,
                        hipFuncAttributeMaxDynamicSharedMemorySize, LDS_SZ);
    gnn_main<true><<<nB, 512, LDS_SZ, stream>>>(x, Wl, blay, Wout, bout,
                                                (const float*)d_ws, out, nB);
  } else {
    hipFuncSetAttribute((const void*)gnn_main<false>,
                        hipFuncAttributeMaxDynamicSharedMemorySize, LDS_SZ);
    gnn_main<false><<<nB, 512, LDS_SZ, stream>>>(x, Wl, blay, Wout, bout,
                                                 (const float*)d_ws, out, nB);
  }
}

// Round 11
// 387.294 us; speedup vs baseline: 1.7145x; 1.2214x over previous
//
#include <hip/hip_runtime.h>
#include <hip/hip_bf16.h>

// ---------------------------------------------------------------------------
// Sudoku GCN, fully fused, MFMA-everything.
//   h_{l+1} = relu( (A+I) h_l * (W_l/21) + b_l ),  A+I exact 0/1 in bf16.
// Orientation ping-pong (no transposed reads, all epi writes b64-packed):
//   hbuf = h^T [feat][node] (chunk-major); agg: g^T = h^T (A+I);
//   gemm: h' = g (W/21); l=6: h6^T = W^T g^T -> h6 [node][feat] for out-GEMM.
// Layer 1 collapsed: h1 = relu(Cnt @ U + b1), U = relu(Win+bin)@W1/21.
// R9: 64-feat g-slices -> 2 independent blocks/CU. R10: per-k-chunk W frags.
// R11: numerics-informed MFMA cut. absmax has been pinned at the bf16-ULP
// comparison floor (2.44e-4 = 2 ULP) for 10 rounds; the dropped gl*w term is
// ~1.6e-5/layer (15x below floor). So: GS stores g hi-plane ONLY (12K),
// W-GEMM + flip use 2 products (gh*wh + gh*wl), agg epi converts hi only.
// MFMA/wave 564->444, GS traffic halves, LDS 68K (2 blocks/CU), W-loop
// liveness drops (kills residual spill). h stays hi/lo (agg stays exact);
// L1 and out-GEMM unchanged.
// ---------------------------------------------------------------------------

typedef short          s16x8 __attribute__((ext_vector_type(8)));
typedef unsigned short u16x8 __attribute__((ext_vector_type(8)));
typedef unsigned short u16x4 __attribute__((ext_vector_type(4)));
typedef float          f32x4 __attribute__((ext_vector_type(4)));

#define HB    0       // hbuf: [2 pl][12 nodechunk][128 feat][16B], plane 24576
#define GS    49152   // gslice: [96 node][64 feat swizzled], hi plane only 12K
#define CNT   61440   // cnt : [4 chunk][96 node][16B] = 6144
#define XC    67584   // x cache: 81 ints
#define LDS_SZ 67968  // x2 = 135936 <= 163840 -> 2 blocks/CU

#define OFF_WB   5120     // [l 0..4][nt 0..7][ks 0..3][pl 0..1] x 1024B
#define OFF_AB   332800   // [nt 0..5][ks 0..2] x 1024B  (A+I, hi only, exact)
#define OFF_UB   351232   // [nt 0..7][pl] x 1024B
#define OFF_WOUT 367616   // [ks 0..3][pl] x 1024B
#define WS_NEED  375808

__device__ __forceinline__ unsigned short f2bf(float f) {   // RTNE via v_cvt
  return __builtin_bit_cast(unsigned short, __float2bfloat16(f));
}
__device__ __forceinline__ float bf2f(unsigned short h) {
  unsigned u = ((unsigned)h) << 16;
  return __builtin_bit_cast(float, u);
}
__device__ __forceinline__ f32x4 mfma16(u16x8 a, u16x8 b, f32x4 c) {
  return __builtin_amdgcn_mfma_f32_16x16x32_bf16(
      __builtin_bit_cast(s16x8, a), __builtin_bit_cast(s16x8, b), c, 0, 0, 0);
}
__device__ __forceinline__ void split4(f32x4 v, u16x4& hi, u16x4& lo) {
#pragma unroll
  for (int r = 0; r < 4; ++r) {
    unsigned short h = f2bf(v[r]);
    hi[r] = h;
    lo[r] = f2bf(v[r] - bf2f(h));
  }
}
__device__ __forceinline__ u16x4 cvt4(f32x4 v) {            // hi-only convert
  u16x4 hi;
#pragma unroll
  for (int r = 0; r < 4; ++r) hi[r] = f2bf(v[r]);
  return hi;
}
__device__ __forceinline__ bool adjf(int r, int c) {
  if (r >= 81 || c >= 81) return false;
  int ri = r / 9, rj = r % 9, ci = c / 9, cj = c % 9;
  return ri == ci || rj == cj || (ri / 3 == ci / 3 && rj / 3 == cj / 3);
}
__device__ __forceinline__ u16x8 makeAB(int nt, int ks, int lane) {
  int col = nt * 16 + (lane & 15), k0 = ks * 32 + (lane >> 4) * 8;
  u16x8 r;
#pragma unroll
  for (int i = 0; i < 8; ++i) r[i] = adjf(k0 + i, col) ? 0x3F80 : 0;
  return r;
}

// ---------------- setup1: U[10][128] = relu(Win+bin) @ W1 / 21 (f32, ws+0) ---
extern "C" __global__ void gnn_setup(const float* __restrict__ Win,
                                     const float* __restrict__ bin,
                                     const float* __restrict__ W1,
                                     float* __restrict__ U) {
  __shared__ float V[1280];
  int t = threadIdx.x;
#pragma unroll
  for (int q = 0; q < 5; ++q) {
    int idx = t + 256 * q;
    V[idx] = fmaxf(Win[idx] + bin[idx & 127], 0.f);
  }
  __syncthreads();
#pragma unroll
  for (int p = 0; p < 5; ++p) {
    int o = t + 256 * p;
    int d = o >> 7, c = o & 127;
    float s = 0.f;
    for (int f = 0; f < 128; ++f) s += V[d * 128 + f] * W1[f * 128 + c];
    U[o] = s * (1.f / 21.f);
  }
}

// ---------------- setup2: pack all B/A fragment blobs into ws ----------------
extern "C" __global__ void gnn_pack(const float* __restrict__ Wl,
                                    const float* __restrict__ Wout,
                                    const float* __restrict__ Uscr,
                                    char* __restrict__ G) {
  int unit = blockIdx.x, lane = threadIdx.x;
  int rsel = lane & 15, kh = lane >> 4;
  u16x8 r;
  char* dst;
  if (unit < 320) {                       // WB: ((l*8+nt)*4+ks)*2+pl
    int pl = unit & 1, ks = (unit >> 1) & 3, nt = (unit >> 3) & 7, l = unit >> 6;
    int col = nt * 16 + rsel, k0 = ks * 32 + kh * 8;
    const float* src = Wl + (l + 1) * 16384 + k0 * 128 + col;
#pragma unroll
    for (int i = 0; i < 8; ++i) {
      float v = src[i * 128] * (1.f / 21.f);
      unsigned short h = f2bf(v);
      r[i] = pl ? f2bf(v - bf2f(h)) : h;
    }
    dst = G + OFF_WB + unit * 1024 + lane * 16;
  } else if (unit < 338) {                // AB: nt*3+ks
    int u2 = unit - 320, nt = u2 / 3, ks = u2 % 3;
    r = makeAB(nt, ks, lane);
    dst = G + OFF_AB + u2 * 1024 + lane * 16;
  } else if (unit < 354) {                // UB: nt*2+pl
    int u2 = unit - 338, nt = u2 >> 1, pl = u2 & 1;
    int col = nt * 16 + rsel;
#pragma unroll
    for (int i = 0; i < 8; ++i) {
      int k = kh * 8 + i;
      float v = (k < 10) ? Uscr[k * 128 + col] : 0.f;
      unsigned short h = f2bf(v);
      r[i] = pl ? f2bf(v - bf2f(h)) : h;
    }
    dst = G + OFF_UB + u2 * 1024 + lane * 16;
  } else {                                // WOUT: ks*2+pl
    int u2 = unit - 354, ks = u2 >> 1, pl = u2 & 1;
    int col = rsel, k0 = ks * 32 + kh * 8;
#pragma unroll
    for (int i = 0; i < 8; ++i) {
      float v = (col < 9) ? Wout[(k0 + i) * 9 + col] : 0.f;
      unsigned short h = f2bf(v);
      r[i] = pl ? f2bf(v - bf2f(h)) : h;
    }
    dst = G + OFF_WOUT + u2 * 1024 + lane * 16;
  }
  *(u16x8*)dst = r;
}

// --------------------------------- main -------------------------------------
template <bool PRE>
__global__ void __launch_bounds__(512, 4)
gnn_main(const int* __restrict__ x, const float* __restrict__ Wl,
         const float* __restrict__ bl, const float* __restrict__ Wout,
         const float* __restrict__ bout, const float* __restrict__ ws,
         float* __restrict__ out, int nB) {
  extern __shared__ char lds[];
  const int t = threadIdx.x, lane = t & 63, w = t >> 6;   // w 0..7
  const int rsel = lane & 15, kh = lane >> 4;
  const char* G = (const char*)ws;
  const int b = blockIdx.x;

  const int ng = w & 1;                  // node triple: ntiles ng*3+{0,1,2}
  const int fg = w >> 1;                 // 0..3: out ftiles fg*2+{0,1};
                                         // agg ftile (per slice s) = s*4+fg

  // ---- persistent A+I B-frags (exact, hi only): 3 ntiles x 3 ks = 36 VGPR --
  u16x8 abf[3][3];
#pragma unroll
  for (int j = 0; j < 3; ++j)
#pragma unroll
    for (int ks = 0; ks < 3; ++ks) {
      if constexpr (PRE)
        abf[j][ks] = *(const u16x8*)(G + OFF_AB + (((ng * 3 + j) * 3 + ks) << 10) + lane * 16);
      else
        abf[j][ks] = makeAB(ng * 3 + j, ks, lane);
    }

  // per-k-chunk W frags: [jf][pl] = 4 frags = 16 VGPR
  u16x8 wb[2][2];
  auto loadWBkk = [&](int blob, int s, int kk) {
#pragma unroll
    for (int jf = 0; jf < 2; ++jf)
#pragma unroll
      for (int pl = 0; pl < 2; ++pl) {
        if constexpr (PRE) {
          wb[jf][pl] = *(const u16x8*)(
              G + OFF_WB +
              ((((blob * 8 + (fg * 2 + jf)) * 4 + (s * 2 + kk)) * 2 + pl) << 10) +
              lane * 16);
        } else {
          int colw = (fg * 2 + jf) * 16 + rsel, k0 = (s * 2 + kk) * 32 + kh * 8;
          const float* src = Wl + (blob + 1) * 16384 + k0 * 128 + colw;
          u16x8 r;
#pragma unroll
          for (int i = 0; i < 8; ++i) {
            float v = src[i * 128] * (1.f / 21.f);
            unsigned short h = f2bf(v);
            r[i] = pl ? f2bf(v - bf2f(h)) : h;
          }
          wb[jf][pl] = r;
        }
      }
  };

  // ---- x cache + digit counts -> cntbuf ----
  if (t < 81) ((int*)(lds + XC))[t] = x[b * 81 + t];
  __syncthreads();
  if (t < 96) {
    unsigned short cnt[16];
#pragma unroll
    for (int d = 0; d < 16; ++d) cnt[d] = 0;
    if (t < 81) {
      const int* xs = (const int*)(lds + XC);
      int n = t, i = n / 9, j = n - 9 * i;
      int bi = (i / 3) * 3, bj = (j / 3) * 3;
      int rv[9], cv[9], bv[9], rb3[3], cb3[3];
#pragma unroll
      for (int k = 0; k < 9; ++k) rv[k] = xs[i * 9 + k];
#pragma unroll
      for (int k = 0; k < 9; ++k) cv[k] = xs[k * 9 + j];
#pragma unroll
      for (int r2 = 0; r2 < 3; ++r2)
#pragma unroll
        for (int c2 = 0; c2 < 3; ++c2) bv[r2 * 3 + c2] = xs[(bi + r2) * 9 + (bj + c2)];
#pragma unroll
      for (int k = 0; k < 3; ++k) rb3[k] = xs[i * 9 + bj + k];
#pragma unroll
      for (int k = 0; k < 3; ++k) cb3[k] = xs[(bi + k) * 9 + j];
#pragma unroll
      for (int d = 0; d < 10; ++d) {
        int c = 0;
#pragma unroll
        for (int k = 0; k < 9; ++k) c += (rv[k] == d) + (cv[k] == d) + (bv[k] == d);
#pragma unroll
        for (int k = 0; k < 3; ++k) c -= (rb3[k] == d) + (cb3[k] == d);
        cnt[d] = f2bf((float)c);         // integers <=21: exact in bf16
      }
    }
    u16x8 c0, c1, z;
#pragma unroll
    for (int e = 0; e < 8; ++e) { c0[e] = cnt[e]; c1[e] = cnt[8 + e]; z[e] = 0; }
    *(u16x8*)(lds + CNT + 0 * 1536 + t * 16) = c0;
    *(u16x8*)(lds + CNT + 1 * 1536 + t * 16) = c1;
    *(u16x8*)(lds + CNT + 2 * 1536 + t * 16) = z;
    *(u16x8*)(lds + CNT + 3 * 1536 + t * 16) = z;
  }
  __syncthreads();

  // ---- L1 GEMM: h1 = relu(Cnt @ U + b1) -> hbuf [feat][node] (3x2 tiles) ---
  {
    u16x8 ubf[2][2];                     // [jf][pl], dead after L1
#pragma unroll
    for (int jf = 0; jf < 2; ++jf)
#pragma unroll
      for (int pl = 0; pl < 2; ++pl) {
        if constexpr (PRE)
          ubf[jf][pl] = *(const u16x8*)(G + OFF_UB + (((fg * 2 + jf) * 2 + pl) << 10) + lane * 16);
        else {
          int col = (fg * 2 + jf) * 16 + rsel;
          u16x8 r;
#pragma unroll
          for (int i = 0; i < 8; ++i) {
            int k = kh * 8 + i;
            float v = (k < 10) ? ws[k * 128 + col] : 0.f;
            unsigned short h = f2bf(v);
            r[i] = pl ? f2bf(v - bf2f(h)) : h;
          }
          ubf[jf][pl] = r;
        }
      }
    float bL1[2];
#pragma unroll
    for (int jf = 0; jf < 2; ++jf) bL1[jf] = bl[(fg * 2 + jf) * 16 + rsel];

    f32x4 a1[3][2];
#pragma unroll
    for (int jn = 0; jn < 3; ++jn)
#pragma unroll
      for (int jf = 0; jf < 2; ++jf) a1[jn][jf] = f32x4{0.f, 0.f, 0.f, 0.f};
#pragma unroll
    for (int jn = 0; jn < 3; ++jn) {
      int node = (ng * 3 + jn) * 16 + rsel;
      u16x8 af = *(const u16x8*)(lds + CNT + kh * 1536 + node * 16);
#pragma unroll
      for (int jf = 0; jf < 2; ++jf) {
        a1[jn][jf] = mfma16(af, ubf[jf][0], a1[jn][jf]);
        a1[jn][jf] = mfma16(af, ubf[jf][1], a1[jn][jf]);
      }
    }
#pragma unroll
    for (int jn = 0; jn < 3; ++jn)
#pragma unroll
      for (int jf = 0; jf < 2; ++jf) {
        int node0 = (ng * 3 + jn) * 16 + kh * 4;
        int feat = (fg * 2 + jf) * 16 + rsel;
        f32x4 v;
#pragma unroll
        for (int r = 0; r < 4; ++r) {
          float u = fmaxf(a1[jn][jf][r] + bL1[jf], 0.f);
          v[r] = (node0 + r < 81) ? u : 0.f;
        }
        u16x4 hi, lo;
        split4(v, hi, lo);
        int base = (node0 >> 3) * 2048 + feat * 16 + (node0 & 7) * 2;
        *(u16x4*)(lds + HB + base) = hi;
        *(u16x4*)(lds + HB + 24576 + base) = lo;
      }
  }

  // agg of one 64-feat slice: g^T tile (ftile s*4+fg, ntiles ng*3+{0..2})
  // exact in f32 (h hi/lo, A 0/1); epi stores g hi-plane ONLY (R11).
  auto do_agg_slice = [&](int s) {
    f32x4 ag[3];
#pragma unroll
    for (int j = 0; j < 3; ++j) ag[j] = f32x4{0.f, 0.f, 0.f, 0.f};
    int feat = (s * 4 + fg) * 16 + rsel;
#pragma unroll
    for (int ks = 0; ks < 3; ++ks) {
      int ba = (ks * 4 + kh) * 2048 + feat * 16;
      u16x8 ah = *(const u16x8*)(lds + HB + ba);
      u16x8 al = *(const u16x8*)(lds + HB + 24576 + ba);
#pragma unroll
      for (int j = 0; j < 3; ++j) {
        ag[j] = mfma16(ah, abf[j][ks], ag[j]);
        ag[j] = mfma16(al, abf[j][ks], ag[j]);
      }
    }
    int wbase = fg * 16 + kh * 4;        // within-slice floc base
    int wfb = wbase >> 3, woff = (wbase & 7) * 2;
#pragma unroll
    for (int j = 0; j < 3; ++j) {
      int node = (ng * 3 + j) * 16 + rsel;
      int ad = node * 128 + (((wfb + node) & 7) << 4) + woff;
      *(u16x4*)(lds + GS + ad) = cvt4(ag[j]);
    }
  };

  // ---- GCN layers 2..5 (l=1..4): per layer 2 slices of K=64 ----
  f32x4 wc[3][2];
#pragma unroll 1
  for (int l = 1; l <= 4; ++l) {
    __syncthreads();                     // HB ready (prev epi)
    float bw[2];
#pragma unroll
    for (int jf = 0; jf < 2; ++jf) bw[jf] = bl[l * 128 + (fg * 2 + jf) * 16 + rsel];
#pragma unroll
    for (int jm = 0; jm < 3; ++jm)
#pragma unroll
      for (int jf = 0; jf < 2; ++jf) wc[jm][jf] = f32x4{0.f, 0.f, 0.f, 0.f};
#pragma unroll
    for (int s = 0; s < 2; ++s) {
      do_agg_slice(s);
      loadWBkk(l - 1, s, 0);             // kk0: hides under agg + barrier
      __syncthreads();                   // GS ready
#pragma unroll
      for (int kk = 0; kk < 2; ++kk) {
#pragma unroll
        for (int jm = 0; jm < 3; ++jm) {
          int node = (ng * 3 + jm) * 16 + rsel;
          int ad = node * 128 + (((4 * kk + kh + node) & 7) << 4);
          u16x8 gh = *(const u16x8*)(lds + GS + ad);
#pragma unroll
          for (int jf = 0; jf < 2; ++jf) {
            wc[jm][jf] = mfma16(gh, wb[jf][0], wc[jm][jf]);
            wc[jm][jf] = mfma16(gh, wb[jf][1], wc[jm][jf]);
          }
        }
        if (kk == 0) loadWBkk(l - 1, s, 1);   // reuse wb regs (WAR, sequential)
      }
      if (s == 0) __syncthreads();       // GS consumed before slice-1 agg
    }
    // epi: bias+relu+mask -> hbuf [feat][node]  (all HB readers done)
#pragma unroll
    for (int jm = 0; jm < 3; ++jm)
#pragma unroll
      for (int jf = 0; jf < 2; ++jf) {
        int node0 = (ng * 3 + jm) * 16 + kh * 4;
        int feat = (fg * 2 + jf) * 16 + rsel;
        f32x4 v;
#pragma unroll
        for (int r = 0; r < 4; ++r) {
          float u = fmaxf(wc[jm][jf][r] + bw[jf], 0.f);
          v[r] = (node0 + r < 81) ? u : 0.f;
        }
        u16x4 hi, lo;
        split4(v, hi, lo);
        int base = (node0 >> 3) * 2048 + feat * 16 + (node0 & 7) * 2;
        *(u16x4*)(lds + HB + base) = hi;
        *(u16x4*)(lds + HB + 24576 + base) = lo;
      }
  }

  // ---- layer 6 (l=5), flipped: h6^T = (W/21)^T g^T, sliced the same way ----
  __syncthreads();                       // HB (h5) ready
  {
    float b5[2][4];
#pragma unroll
    for (int jf = 0; jf < 2; ++jf)
#pragma unroll
      for (int r = 0; r < 4; ++r)
        b5[jf][r] = bl[5 * 128 + (fg * 2 + jf) * 16 + kh * 4 + r];
    f32x4 w6[2][3];
#pragma unroll
    for (int jf = 0; jf < 2; ++jf)
#pragma unroll
      for (int jn = 0; jn < 3; ++jn) w6[jf][jn] = f32x4{0.f, 0.f, 0.f, 0.f};
#pragma unroll
    for (int s = 0; s < 2; ++s) {
      do_agg_slice(s);
      loadWBkk(4, s, 0);
      __syncthreads();                   // GS ready
#pragma unroll
      for (int kk = 0; kk < 2; ++kk) {
#pragma unroll
        for (int jn = 0; jn < 3; ++jn) {
          int node = (ng * 3 + jn) * 16 + rsel;
          int ad = node * 128 + (((4 * kk + kh + node) & 7) << 4);
          u16x8 gh = *(const u16x8*)(lds + GS + ad);
#pragma unroll
          for (int jf = 0; jf < 2; ++jf) {
            w6[jf][jn] = mfma16(wb[jf][0], gh, w6[jf][jn]);
            w6[jf][jn] = mfma16(wb[jf][1], gh, w6[jf][jn]);
          }
        }
        if (kk == 0) loadWBkk(4, s, 1);
      }
      if (s == 0) __syncthreads();
    }
    // epi: C row=feat_out(4 consec), col=node -> h6 [node][feat] into HB
#pragma unroll
    for (int jf = 0; jf < 2; ++jf)
#pragma unroll
      for (int jn = 0; jn < 3; ++jn) {
        int node = (ng * 3 + jn) * 16 + rsel;
        int f0 = (fg * 2 + jf) * 16 + kh * 4;
        f32x4 v;
#pragma unroll
        for (int r = 0; r < 4; ++r) {
          float u = fmaxf(w6[jf][jn][r] + b5[jf][r], 0.f);
          v[r] = (node < 81) ? u : 0.f;
        }
        u16x4 hi, lo;
        split4(v, hi, lo);
        int base = (f0 >> 3) * 1536 + node * 16 + (f0 & 7) * 2;
        *(u16x4*)(lds + HB + base) = hi;
        *(u16x4*)(lds + HB + 24576 + base) = lo;
      }
  }

  // ---- output GEMM: logits = h6 @ Wout + bout (waves 0..5, 1 tile each) ----
  u16x8 wo[4][2];
  if (w < 6) {
#pragma unroll
    for (int ks = 0; ks < 4; ++ks)
#pragma unroll
      for (int pl = 0; pl < 2; ++pl) {
        if constexpr (PRE)
          wo[ks][pl] = *(const u16x8*)(G + OFF_WOUT + (ks * 2 + pl) * 1024 + lane * 16);
        else {
          int col = rsel, k0 = ks * 32 + kh * 8;
          u16x8 r;
#pragma unroll
          for (int i = 0; i < 8; ++i) {
            float v = (col < 9) ? Wout[(k0 + i) * 9 + col] : 0.f;
            unsigned short h = f2bf(v);
            r[i] = pl ? f2bf(v - bf2f(h)) : h;
          }
          wo[ks][pl] = r;
        }
      }
  }
  __syncthreads();
  if (w < 6) {
    f32x4 oc = f32x4{0.f, 0.f, 0.f, 0.f};
#pragma unroll
    for (int ks = 0; ks < 4; ++ks) {
      int node = w * 16 + rsel;
      int ba = (ks * 4 + kh) * 1536 + node * 16;
      u16x8 hh = *(const u16x8*)(lds + HB + ba);
      u16x8 hl = *(const u16x8*)(lds + HB + 24576 + ba);
      oc = mfma16(hh, wo[ks][0], oc);
      oc = mfma16(hh, wo[ks][1], oc);
      oc = mfma16(hl, wo[ks][0], oc);
    }
    int colo = rsel;
    if (colo < 9) {
      float bo = bout[colo];
#pragma unroll
      for (int r = 0; r < 4; ++r) {
        int node = w * 16 + kh * 4 + r;
        if (node < 81) out[b * 729 + node * 9 + colo] = oc[r] + bo;
      }
    }
  }
}

// ------------------------------- launcher ------------------------------------
extern "C" void kernel_launch(void* const* d_in, const int* in_sizes, int n_in,
                              void* d_out, int out_size, void* d_ws, size_t ws_size,
                              hipStream_t stream) {
  const int*   x    = (const int*)d_in[0];
  const float* Win  = (const float*)d_in[1];
  const float* bin  = (const float*)d_in[2];
  const float* Wl   = (const float*)d_in[3];
  const float* blay = (const float*)d_in[4];
  const float* Wout = (const float*)d_in[5];
  const float* bout = (const float*)d_in[6];
  float* out = (float*)d_out;
  int nB = in_sizes[0] / 81;

  bool pre = ws_size >= WS_NEED;
  gnn_setup<<<1, 256, 0, stream>>>(Win, bin, Wl, (float*)d_ws);     // U -> ws+0
  if (pre)
    gnn_pack<<<362, 64, 0, stream>>>(Wl, Wout, (const float*)d_ws, (char*)d_ws);

  if (pre) {
    hipFuncSetAttribute((const void*)gnn_main<true>,
                        hipFuncAttributeMaxDynamicSharedMemorySize, LDS_SZ);
    gnn_main<true><<<nB, 512, LDS_SZ, stream>>>(x, Wl, blay, Wout, bout,
                                                (const float*)d_ws, out, nB);
  } else {
    hipFuncSetAttribute((const void*)gnn_main<false>,
                        hipFuncAttributeMaxDynamicSharedMemorySize, LDS_SZ);
    gnn_main<false><<<nB, 512, LDS_SZ, stream>>>(x, Wl, blay, Wout, bout,
                                                 (const float*)d_ws, out, nB);
  }
}

// Round 12
// 318.764 us; speedup vs baseline: 2.0831x; 1.2150x over previous
//
#include <hip/hip_runtime.h>
#include <hip/hip_bf16.h>

// ---------------------------------------------------------------------------
// Sudoku GCN, fully fused, MFMA-everything.
//   h_{l+1} = relu( (A+I) h_l * (W_l/21) + b_l ),  A+I exact 0/1 in bf16.
// Orientation ping-pong (no transposed reads, all epi writes packed):
//   hbuf = h^T [feat][node] (chunk-major); agg: g^T = h^T (A+I);
//   gemm: h' = g (W/21); l=6: h6^T = W^T g^T -> h6 [node][feat] for out-GEMM.
// Layer 1 collapsed: h1 = relu(Cnt @ U + b1), U = relu(Win+bin)@W1/21.
// R9: 64-feat g-slices -> 2 independent blocks/CU. R10: per-k-chunk W frags.
// R11: g stored hi-only (absmax pinned at 2-ULP comparison floor).
// R12: h stored hi-only too (error budget: ~0.08%/layer rel, ~5 layers,
// logits max 0.0376 -> adds <2e-4 abs; threshold 7.5e-4, we were at 2.44e-4).
// Payoff: agg 1-product (MFMA/wave 444->348), HB 48K->24K, freed LDS ->
// GS DOUBLE-BUFFER: mid-slice barrier gone (4->3/layer) and agg(slice1)
// interleaves with W(slice0) (independent MFMA chains). Epilogues hi-only.
// W keeps hi/lo (2-product); L1 keeps exact Cnt + U hi/lo.
// ---------------------------------------------------------------------------

typedef short          s16x8 __attribute__((ext_vector_type(8)));
typedef unsigned short u16x8 __attribute__((ext_vector_type(8)));
typedef unsigned short u16x4 __attribute__((ext_vector_type(4)));
typedef float          f32x4 __attribute__((ext_vector_type(4)));

#define HB    0       // hbuf: [12 nodechunk][128 feat][16B] hi only = 24576
                      // (l6: h6 as [16 fchunk][96 node][16B] = 24576, reused)
#define GS0   24576   // gslice 0: [96 node][64 feat swizzled] hi = 12288
#define GS1   36864   // gslice 1: ditto
#define CNT   49152   // cnt : [4 chunk][96 node][16B] = 6144
#define XC    55296   // x cache: 81 ints
#define LDS_SZ 55680  // x2 = 111360 <= 163840 -> 2 blocks/CU

#define OFF_WB   5120     // [l 0..4][nt 0..7][ks 0..3][pl 0..1] x 1024B
#define OFF_AB   332800   // [nt 0..5][ks 0..2] x 1024B  (A+I, hi only, exact)
#define OFF_UB   351232   // [nt 0..7][pl] x 1024B
#define OFF_WOUT 367616   // [ks 0..3][pl] x 1024B
#define WS_NEED  375808

__device__ __forceinline__ unsigned short f2bf(float f) {   // RTNE via v_cvt
  return __builtin_bit_cast(unsigned short, __float2bfloat16(f));
}
__device__ __forceinline__ float bf2f(unsigned short h) {
  unsigned u = ((unsigned)h) << 16;
  return __builtin_bit_cast(float, u);
}
__device__ __forceinline__ f32x4 mfma16(u16x8 a, u16x8 b, f32x4 c) {
  return __builtin_amdgcn_mfma_f32_16x16x32_bf16(
      __builtin_bit_cast(s16x8, a), __builtin_bit_cast(s16x8, b), c, 0, 0, 0);
}
__device__ __forceinline__ u16x4 cvt4(f32x4 v) {            // hi-only convert
  u16x4 hi;
#pragma unroll
  for (int r = 0; r < 4; ++r) hi[r] = f2bf(v[r]);
  return hi;
}
__device__ __forceinline__ bool adjf(int r, int c) {
  if (r >= 81 || c >= 81) return false;
  int ri = r / 9, rj = r % 9, ci = c / 9, cj = c % 9;
  return ri == ci || rj == cj || (ri / 3 == ci / 3 && rj / 3 == cj / 3);
}
__device__ __forceinline__ u16x8 makeAB(int nt, int ks, int lane) {
  int col = nt * 16 + (lane & 15), k0 = ks * 32 + (lane >> 4) * 8;
  u16x8 r;
#pragma unroll
  for (int i = 0; i < 8; ++i) r[i] = adjf(k0 + i, col) ? 0x3F80 : 0;
  return r;
}

// ---------------- setup1: U[10][128] = relu(Win+bin) @ W1 / 21 (f32, ws+0) ---
extern "C" __global__ void gnn_setup(const float* __restrict__ Win,
                                     const float* __restrict__ bin,
                                     const float* __restrict__ W1,
                                     float* __restrict__ U) {
  __shared__ float V[1280];
  int t = threadIdx.x;
#pragma unroll
  for (int q = 0; q < 5; ++q) {
    int idx = t + 256 * q;
    V[idx] = fmaxf(Win[idx] + bin[idx & 127], 0.f);
  }
  __syncthreads();
#pragma unroll
  for (int p = 0; p < 5; ++p) {
    int o = t + 256 * p;
    int d = o >> 7, c = o & 127;
    float s = 0.f;
    for (int f = 0; f < 128; ++f) s += V[d * 128 + f] * W1[f * 128 + c];
    U[o] = s * (1.f / 21.f);
  }
}

// ---------------- setup2: pack all B/A fragment blobs into ws ----------------
extern "C" __global__ void gnn_pack(const float* __restrict__ Wl,
                                    const float* __restrict__ Wout,
                                    const float* __restrict__ Uscr,
                                    char* __restrict__ G) {
  int unit = blockIdx.x, lane = threadIdx.x;
  int rsel = lane & 15, kh = lane >> 4;
  u16x8 r;
  char* dst;
  if (unit < 320) {                       // WB: ((l*8+nt)*4+ks)*2+pl
    int pl = unit & 1, ks = (unit >> 1) & 3, nt = (unit >> 3) & 7, l = unit >> 6;
    int col = nt * 16 + rsel, k0 = ks * 32 + kh * 8;
    const float* src = Wl + (l + 1) * 16384 + k0 * 128 + col;
#pragma unroll
    for (int i = 0; i < 8; ++i) {
      float v = src[i * 128] * (1.f / 21.f);
      unsigned short h = f2bf(v);
      r[i] = pl ? f2bf(v - bf2f(h)) : h;
    }
    dst = G + OFF_WB + unit * 1024 + lane * 16;
  } else if (unit < 338) {                // AB: nt*3+ks
    int u2 = unit - 320, nt = u2 / 3, ks = u2 % 3;
    r = makeAB(nt, ks, lane);
    dst = G + OFF_AB + u2 * 1024 + lane * 16;
  } else if (unit < 354) {                // UB: nt*2+pl
    int u2 = unit - 338, nt = u2 >> 1, pl = u2 & 1;
    int col = nt * 16 + rsel;
#pragma unroll
    for (int i = 0; i < 8; ++i) {
      int k = kh * 8 + i;
      float v = (k < 10) ? Uscr[k * 128 + col] : 0.f;
      unsigned short h = f2bf(v);
      r[i] = pl ? f2bf(v - bf2f(h)) : h;
    }
    dst = G + OFF_UB + u2 * 1024 + lane * 16;
  } else {                                // WOUT: ks*2+pl
    int u2 = unit - 354, ks = u2 >> 1, pl = u2 & 1;
    int col = rsel, k0 = ks * 32 + kh * 8;
#pragma unroll
    for (int i = 0; i < 8; ++i) {
      float v = (col < 9) ? Wout[(k0 + i) * 9 + col] : 0.f;
      unsigned short h = f2bf(v);
      r[i] = pl ? f2bf(v - bf2f(h)) : h;
    }
    dst = G + OFF_WOUT + u2 * 1024 + lane * 16;
  }
  *(u16x8*)dst = r;
}

// --------------------------------- main -------------------------------------
template <bool PRE>
__global__ void __launch_bounds__(512, 4)
gnn_main(const int* __restrict__ x, const float* __restrict__ Wl,
         const float* __restrict__ bl, const float* __restrict__ Wout,
         const float* __restrict__ bout, const float* __restrict__ ws,
         float* __restrict__ out, int nB) {
  extern __shared__ char lds[];
  const int t = threadIdx.x, lane = t & 63, w = t >> 6;   // w 0..7
  const int rsel = lane & 15, kh = lane >> 4;
  const char* G = (const char*)ws;
  const int b = blockIdx.x;

  const int ng = w & 1;                  // node triple: ntiles ng*3+{0,1,2}
  const int fg = w >> 1;                 // 0..3: out ftiles fg*2+{0,1};
                                         // agg ftile (per slice s) = s*4+fg

  // ---- persistent A+I B-frags (exact, hi only): 3 ntiles x 3 ks = 36 VGPR --
  u16x8 abf[3][3];
#pragma unroll
  for (int j = 0; j < 3; ++j)
#pragma unroll
    for (int ks = 0; ks < 3; ++ks) {
      if constexpr (PRE)
        abf[j][ks] = *(const u16x8*)(G + OFF_AB + (((ng * 3 + j) * 3 + ks) << 10) + lane * 16);
      else
        abf[j][ks] = makeAB(ng * 3 + j, ks, lane);
    }

  // per-k-chunk W frags: [jf][pl] = 4 frags = 16 VGPR
  u16x8 wb[2][2];
  auto loadWBkk = [&](int blob, int s, int kk) {
#pragma unroll
    for (int jf = 0; jf < 2; ++jf)
#pragma unroll
      for (int pl = 0; pl < 2; ++pl) {
        if constexpr (PRE) {
          wb[jf][pl] = *(const u16x8*)(
              G + OFF_WB +
              ((((blob * 8 + (fg * 2 + jf)) * 4 + (s * 2 + kk)) * 2 + pl) << 10) +
              lane * 16);
        } else {
          int colw = (fg * 2 + jf) * 16 + rsel, k0 = (s * 2 + kk) * 32 + kh * 8;
          const float* src = Wl + (blob + 1) * 16384 + k0 * 128 + colw;
          u16x8 r;
#pragma unroll
          for (int i = 0; i < 8; ++i) {
            float v = src[i * 128] * (1.f / 21.f);
            unsigned short h = f2bf(v);
            r[i] = pl ? f2bf(v - bf2f(h)) : h;
          }
          wb[jf][pl] = r;
        }
      }
  };

  // ---- x cache + digit counts -> cntbuf ----
  if (t < 81) ((int*)(lds + XC))[t] = x[b * 81 + t];
  __syncthreads();
  if (t < 96) {
    unsigned short cnt[16];
#pragma unroll
    for (int d = 0; d < 16; ++d) cnt[d] = 0;
    if (t < 81) {
      const int* xs = (const int*)(lds + XC);
      int n = t, i = n / 9, j = n - 9 * i;
      int bi = (i / 3) * 3, bj = (j / 3) * 3;
      int rv[9], cv[9], bv[9], rb3[3], cb3[3];
#pragma unroll
      for (int k = 0; k < 9; ++k) rv[k] = xs[i * 9 + k];
#pragma unroll
      for (int k = 0; k < 9; ++k) cv[k] = xs[k * 9 + j];
#pragma unroll
      for (int r2 = 0; r2 < 3; ++r2)
#pragma unroll
        for (int c2 = 0; c2 < 3; ++c2) bv[r2 * 3 + c2] = xs[(bi + r2) * 9 + (bj + c2)];
#pragma unroll
      for (int k = 0; k < 3; ++k) rb3[k] = xs[i * 9 + bj + k];
#pragma unroll
      for (int k = 0; k < 3; ++k) cb3[k] = xs[(bi + k) * 9 + j];
#pragma unroll
      for (int d = 0; d < 10; ++d) {
        int c = 0;
#pragma unroll
        for (int k = 0; k < 9; ++k) c += (rv[k] == d) + (cv[k] == d) + (bv[k] == d);
#pragma unroll
        for (int k = 0; k < 3; ++k) c -= (rb3[k] == d) + (cb3[k] == d);
        cnt[d] = f2bf((float)c);         // integers <=21: exact in bf16
      }
    }
    u16x8 c0, c1, z;
#pragma unroll
    for (int e = 0; e < 8; ++e) { c0[e] = cnt[e]; c1[e] = cnt[8 + e]; z[e] = 0; }
    *(u16x8*)(lds + CNT + 0 * 1536 + t * 16) = c0;
    *(u16x8*)(lds + CNT + 1 * 1536 + t * 16) = c1;
    *(u16x8*)(lds + CNT + 2 * 1536 + t * 16) = z;
    *(u16x8*)(lds + CNT + 3 * 1536 + t * 16) = z;
  }
  __syncthreads();

  // ---- L1 GEMM: h1 = relu(Cnt @ U + b1) -> hbuf [feat][node] (3x2 tiles) ---
  {
    u16x8 ubf[2][2];                     // [jf][pl], dead after L1
#pragma unroll
    for (int jf = 0; jf < 2; ++jf)
#pragma unroll
      for (int pl = 0; pl < 2; ++pl) {
        if constexpr (PRE)
          ubf[jf][pl] = *(const u16x8*)(G + OFF_UB + (((fg * 2 + jf) * 2 + pl) << 10) + lane * 16);
        else {
          int col = (fg * 2 + jf) * 16 + rsel;
          u16x8 r;
#pragma unroll
          for (int i = 0; i < 8; ++i) {
            int k = kh * 8 + i;
            float v = (k < 10) ? ws[k * 128 + col] : 0.f;
            unsigned short h = f2bf(v);
            r[i] = pl ? f2bf(v - bf2f(h)) : h;
          }
          ubf[jf][pl] = r;
        }
      }
    float bL1[2];
#pragma unroll
    for (int jf = 0; jf < 2; ++jf) bL1[jf] = bl[(fg * 2 + jf) * 16 + rsel];

    f32x4 a1[3][2];
#pragma unroll
    for (int jn = 0; jn < 3; ++jn)
#pragma unroll
      for (int jf = 0; jf < 2; ++jf) a1[jn][jf] = f32x4{0.f, 0.f, 0.f, 0.f};
#pragma unroll
    for (int jn = 0; jn < 3; ++jn) {
      int node = (ng * 3 + jn) * 16 + rsel;
      u16x8 af = *(const u16x8*)(lds + CNT + kh * 1536 + node * 16);
#pragma unroll
      for (int jf = 0; jf < 2; ++jf) {
        a1[jn][jf] = mfma16(af, ubf[jf][0], a1[jn][jf]);
        a1[jn][jf] = mfma16(af, ubf[jf][1], a1[jn][jf]);
      }
    }
#pragma unroll
    for (int jn = 0; jn < 3; ++jn)
#pragma unroll
      for (int jf = 0; jf < 2; ++jf) {
        int node0 = (ng * 3 + jn) * 16 + kh * 4;
        int feat = (fg * 2 + jf) * 16 + rsel;
        f32x4 v;
#pragma unroll
        for (int r = 0; r < 4; ++r) {
          float u = fmaxf(a1[jn][jf][r] + bL1[jf], 0.f);
          v[r] = (node0 + r < 81) ? u : 0.f;
        }
        int base = (node0 >> 3) * 2048 + feat * 16 + (node0 & 7) * 2;
        *(u16x4*)(lds + HB + base) = cvt4(v);
      }
  }

  // agg of one 64-feat slice -> GS0/GS1 (1-product: h hi-only, A exact)
  auto do_agg_slice = [&](int s) {
    f32x4 ag[3];
#pragma unroll
    for (int j = 0; j < 3; ++j) ag[j] = f32x4{0.f, 0.f, 0.f, 0.f};
    int feat = (s * 4 + fg) * 16 + rsel;
#pragma unroll
    for (int ks = 0; ks < 3; ++ks) {
      int ba = (ks * 4 + kh) * 2048 + feat * 16;
      u16x8 ah = *(const u16x8*)(lds + HB + ba);
#pragma unroll
      for (int j = 0; j < 3; ++j) ag[j] = mfma16(ah, abf[j][ks], ag[j]);
    }
    int gsb = GS0 + s * 12288;
    int wbase = fg * 16 + kh * 4;        // within-slice floc base
    int wfb = wbase >> 3, woff = (wbase & 7) * 2;
#pragma unroll
    for (int j = 0; j < 3; ++j) {
      int node = (ng * 3 + j) * 16 + rsel;
      int ad = node * 128 + (((wfb + node) & 7) << 4) + woff;
      *(u16x4*)(lds + gsb + ad) = cvt4(ag[j]);
    }
  };

  // W accumulate one slice from GS[s] (2-product: g hi x W hi/lo)
  f32x4 wc[3][2];
  auto do_W_slice = [&](int blob, int s) {
    int gsb = GS0 + s * 12288;
#pragma unroll
    for (int kk = 0; kk < 2; ++kk) {
#pragma unroll
      for (int jm = 0; jm < 3; ++jm) {
        int node = (ng * 3 + jm) * 16 + rsel;
        int ad = node * 128 + (((4 * kk + kh + node) & 7) << 4);
        u16x8 gh = *(const u16x8*)(lds + gsb + ad);
#pragma unroll
        for (int jf = 0; jf < 2; ++jf) {
          wc[jm][jf] = mfma16(gh, wb[jf][0], wc[jm][jf]);
          wc[jm][jf] = mfma16(gh, wb[jf][1], wc[jm][jf]);
        }
      }
      if (kk == 0) loadWBkk(blob, s, 1);      // reuse wb regs (WAR, sequential)
    }
  };

  // ---- GCN layers 2..5 (l=1..4): 2 slices, GS double-buffered, 3 barriers --
#pragma unroll 1
  for (int l = 1; l <= 4; ++l) {
    __syncthreads();                     // HB ready (prev epi)
    float bw[2];
#pragma unroll
    for (int jf = 0; jf < 2; ++jf) bw[jf] = bl[l * 128 + (fg * 2 + jf) * 16 + rsel];
#pragma unroll
    for (int jm = 0; jm < 3; ++jm)
#pragma unroll
      for (int jf = 0; jf < 2; ++jf) wc[jm][jf] = f32x4{0.f, 0.f, 0.f, 0.f};

    do_agg_slice(0);                     // -> GS0
    loadWBkk(l - 1, 0, 0);               // hides under agg + barrier
    __syncthreads();                     // GS0 ready
    do_agg_slice(1);                     // -> GS1 (interleaves with W(0))
    do_W_slice(l - 1, 0);                // reads GS0
    loadWBkk(l - 1, 1, 0);
    __syncthreads();                     // GS1 ready (also: all HB reads done)
    do_W_slice(l - 1, 1);                // reads GS1
    // epi: bias+relu+mask -> hbuf [feat][node] hi-only
#pragma unroll
    for (int jm = 0; jm < 3; ++jm)
#pragma unroll
      for (int jf = 0; jf < 2; ++jf) {
        int node0 = (ng * 3 + jm) * 16 + kh * 4;
        int feat = (fg * 2 + jf) * 16 + rsel;
        f32x4 v;
#pragma unroll
        for (int r = 0; r < 4; ++r) {
          float u = fmaxf(wc[jm][jf][r] + bw[jf], 0.f);
          v[r] = (node0 + r < 81) ? u : 0.f;
        }
        int base = (node0 >> 3) * 2048 + feat * 16 + (node0 & 7) * 2;
        *(u16x4*)(lds + HB + base) = cvt4(v);
      }
  }

  // ---- layer 6 (l=5), flipped: h6^T = (W/21)^T g^T, same 3-barrier shape ---
  __syncthreads();                       // HB (h5) ready
  {
    float b5[2][4];
#pragma unroll
    for (int jf = 0; jf < 2; ++jf)
#pragma unroll
      for (int r = 0; r < 4; ++r)
        b5[jf][r] = bl[5 * 128 + (fg * 2 + jf) * 16 + kh * 4 + r];
    f32x4 w6[2][3];
#pragma unroll
    for (int jf = 0; jf < 2; ++jf)
#pragma unroll
      for (int jn = 0; jn < 3; ++jn) w6[jf][jn] = f32x4{0.f, 0.f, 0.f, 0.f};

    auto do_flip_slice = [&](int s) {
      int gsb = GS0 + s * 12288;
#pragma unroll
      for (int kk = 0; kk < 2; ++kk) {
#pragma unroll
        for (int jn = 0; jn < 3; ++jn) {
          int node = (ng * 3 + jn) * 16 + rsel;
          int ad = node * 128 + (((4 * kk + kh + node) & 7) << 4);
          u16x8 gh = *(const u16x8*)(lds + gsb + ad);
#pragma unroll
          for (int jf = 0; jf < 2; ++jf) {
            w6[jf][jn] = mfma16(wb[jf][0], gh, w6[jf][jn]);
            w6[jf][jn] = mfma16(wb[jf][1], gh, w6[jf][jn]);
          }
        }
        if (kk == 0) loadWBkk(4, s, 1);
      }
    };

    do_agg_slice(0);
    loadWBkk(4, 0, 0);
    __syncthreads();                     // GS0 ready
    do_agg_slice(1);
    do_flip_slice(0);
    loadWBkk(4, 1, 0);
    __syncthreads();                     // GS1 ready (all HB h5 reads done)
    do_flip_slice(1);
    // epi: C row=feat_out(4 consec), col=node -> h6 [node][feat] into HB
#pragma unroll
    for (int jf = 0; jf < 2; ++jf)
#pragma unroll
      for (int jn = 0; jn < 3; ++jn) {
        int node = (ng * 3 + jn) * 16 + rsel;
        int f0 = (fg * 2 + jf) * 16 + kh * 4;
        f32x4 v;
#pragma unroll
        for (int r = 0; r < 4; ++r) {
          float u = fmaxf(w6[jf][jn][r] + b5[jf][r], 0.f);
          v[r] = (node < 81) ? u : 0.f;
        }
        int base = (f0 >> 3) * 1536 + node * 16 + (f0 & 7) * 2;
        *(u16x4*)(lds + HB + base) = cvt4(v);
      }
  }

  // ---- output GEMM: logits = h6 @ Wout + bout (waves 0..5, 1 tile each) ----
  u16x8 wo[4][2];
  if (w < 6) {
#pragma unroll
    for (int ks = 0; ks < 4; ++ks)
#pragma unroll
      for (int pl = 0; pl < 2; ++pl) {
        if constexpr (PRE)
          wo[ks][pl] = *(const u16x8*)(G + OFF_WOUT + (ks * 2 + pl) * 1024 + lane * 16);
        else {
          int col = rsel, k0 = ks * 32 + kh * 8;
          u16x8 r;
#pragma unroll
          for (int i = 0; i < 8; ++i) {
            float v = (col < 9) ? Wout[(k0 + i) * 9 + col] : 0.f;
            unsigned short h = f2bf(v);
            r[i] = pl ? f2bf(v - bf2f(h)) : h;
          }
          wo[ks][pl] = r;
        }
      }
  }
  __syncthreads();
  if (w < 6) {
    f32x4 oc = f32x4{0.f, 0.f, 0.f, 0.f};
#pragma unroll
    for (int ks = 0; ks < 4; ++ks) {
      int node = w * 16 + rsel;
      int ba = (ks * 4 + kh) * 1536 + node * 16;
      u16x8 hh = *(const u16x8*)(lds + HB + ba);
      oc = mfma16(hh, wo[ks][0], oc);
      oc = mfma16(hh, wo[ks][1], oc);
    }
    int colo = rsel;
    if (colo < 9) {
      float bo = bout[colo];
#pragma unroll
      for (int r = 0; r < 4; ++r) {
        int node = w * 16 + kh * 4 + r;
        if (node < 81) out[b * 729 + node * 9 + colo] = oc[r] + bo;
      }
    }
  }
}

// ------------------------------- launcher ------------------------------------
extern "C" void kernel_launch(void* const* d_in, const int* in_sizes, int n_in,
                              void* d_out, int out_size, void* d_ws, size_t ws_size,
                              hipStream_t stream) {
  const int*   x    = (const int*)d_in[0];
  const float* Win  = (const float*)d_in[1];
  const float* bin  = (const float*)d_in[2];
  const float* Wl   = (const float*)d_in[3];
  const float* blay = (const float*)d_in[4];
  const float* Wout = (const float*)d_in[5];
  const float* bout = (const float*)d_in[6];
  float* out = (float*)d_out;
  int nB = in_sizes[0] / 81;

  bool pre = ws_size >= WS_NEED;
  gnn_setup<<<1, 256, 0, stream>>>(Win, bin, Wl, (float*)d_ws);     // U -> ws+0
  if (pre)
    gnn_pack<<<362, 64, 0, stream>>>(Wl, Wout, (const float*)d_ws, (char*)d_ws);

  if (pre) {
    hipFuncSetAttribute((const void*)gnn_main<true>,
                        hipFuncAttributeMaxDynamicSharedMemorySize, LDS_SZ);
    gnn_main<true><<<nB, 512, LDS_SZ, stream>>>(x, Wl, blay, Wout, bout,
                                                (const float*)d_ws, out, nB);
  } else {
    hipFuncSetAttribute((const void*)gnn_main<false>,
                        hipFuncAttributeMaxDynamicSharedMemorySize, LDS_SZ);
    gnn_main<false><<<nB, 512, LDS_SZ, stream>>>(x, Wl, blay, Wout, bout,
                                                 (const float*)d_ws, out, nB);
  }
}

// Round 13
// 250.881 us; speedup vs baseline: 2.6467x; 1.2706x over previous
//
#include <hip/hip_runtime.h>
#include <hip/hip_bf16.h>

// ---------------------------------------------------------------------------
// Sudoku GCN, fully fused, MFMA-everything.
//   h_{l+1} = relu( (A+I) h_l * (W_l/21) + b_l ),  A+I exact 0/1 in bf16.
// Orientation ping-pong (no transposed reads, all epi writes packed):
//   hbuf = h^T [feat][node] (chunk-major); agg: g^T = h^T (A+I);
//   gemm: h' = g (W/21); l=6: h6^T = W^T g^T -> h6 [node][feat] for out-GEMM.
// Layer 1 collapsed: h1 = relu(Cnt @ U + b1), U = relu(Win+bin)@W1/21.
// R9: 64-feat g-slices, 2 blocks/CU. R10: per-k-chunk W frags. R11: g hi-only.
// R12: h hi-only + GS double-buffer (3 barriers/layer). absmax NEVER moved
// off the 2-ULP comparison floor (2.44e-4) through R11+R12 -> error model
// runs high; averaging (A/21)+relu damp quantization noise.
// R13: W hi-only in layers 2..6 (1-product W-GEMM/flip). Error arith:
// 2^-9/sqrt(3) ~ 0.11%/layer rel, ~0.6% compounded ~ 2.2e-4 abs — inside
// the 7.5e-4 threshold with our 2.44e-4 base. MFMA/wave 348->230 (we are
// exactly at the MFMA-issue floor: MfmaUtil 46.7% = 27K/54K cyc). wb = one
// per-slice load of 4 hi frags (16 VGPR, no mid-loop reload; slice-1 load
// placed after W(slice0) to avoid WAR on live regs, hides under barrier).
// L1 stays exact (Cnt int + U hi/lo); out-GEMM keeps Wout hi/lo (4 MFMAs,
// feeds logits directly).
// ---------------------------------------------------------------------------

typedef short          s16x8 __attribute__((ext_vector_type(8)));
typedef unsigned short u16x8 __attribute__((ext_vector_type(8)));
typedef unsigned short u16x4 __attribute__((ext_vector_type(4)));
typedef float          f32x4 __attribute__((ext_vector_type(4)));

#define HB    0       // hbuf: [12 nodechunk][128 feat][16B] hi only = 24576
                      // (l6: h6 as [16 fchunk][96 node][16B] = 24576, reused)
#define GS0   24576   // gslice 0: [96 node][64 feat swizzled] hi = 12288
#define GS1   36864   // gslice 1: ditto
#define CNT   49152   // cnt : [4 chunk][96 node][16B] = 6144
#define XC    55296   // x cache: 81 ints
#define LDS_SZ 55680  // x2 = 111360 <= 163840 -> 2 blocks/CU

#define OFF_WB   5120     // [l 0..4][nt 0..7][ks 0..3][pl 0..1] x 1024B
#define OFF_AB   332800   // [nt 0..5][ks 0..2] x 1024B  (A+I, hi only, exact)
#define OFF_UB   351232   // [nt 0..7][pl] x 1024B
#define OFF_WOUT 367616   // [ks 0..3][pl] x 1024B
#define WS_NEED  375808

__device__ __forceinline__ unsigned short f2bf(float f) {   // RTNE via v_cvt
  return __builtin_bit_cast(unsigned short, __float2bfloat16(f));
}
__device__ __forceinline__ float bf2f(unsigned short h) {
  unsigned u = ((unsigned)h) << 16;
  return __builtin_bit_cast(float, u);
}
__device__ __forceinline__ f32x4 mfma16(u16x8 a, u16x8 b, f32x4 c) {
  return __builtin_amdgcn_mfma_f32_16x16x32_bf16(
      __builtin_bit_cast(s16x8, a), __builtin_bit_cast(s16x8, b), c, 0, 0, 0);
}
__device__ __forceinline__ u16x4 cvt4(f32x4 v) {            // hi-only convert
  u16x4 hi;
#pragma unroll
  for (int r = 0; r < 4; ++r) hi[r] = f2bf(v[r]);
  return hi;
}
__device__ __forceinline__ bool adjf(int r, int c) {
  if (r >= 81 || c >= 81) return false;
  int ri = r / 9, rj = r % 9, ci = c / 9, cj = c % 9;
  return ri == ci || rj == cj || (ri / 3 == ci / 3 && rj / 3 == cj / 3);
}
__device__ __forceinline__ u16x8 makeAB(int nt, int ks, int lane) {
  int col = nt * 16 + (lane & 15), k0 = ks * 32 + (lane >> 4) * 8;
  u16x8 r;
#pragma unroll
  for (int i = 0; i < 8; ++i) r[i] = adjf(k0 + i, col) ? 0x3F80 : 0;
  return r;
}

// ---------------- setup1: U[10][128] = relu(Win+bin) @ W1 / 21 (f32, ws+0) ---
extern "C" __global__ void gnn_setup(const float* __restrict__ Win,
                                     const float* __restrict__ bin,
                                     const float* __restrict__ W1,
                                     float* __restrict__ U) {
  __shared__ float V[1280];
  int t = threadIdx.x;
#pragma unroll
  for (int q = 0; q < 5; ++q) {
    int idx = t + 256 * q;
    V[idx] = fmaxf(Win[idx] + bin[idx & 127], 0.f);
  }
  __syncthreads();
#pragma unroll
  for (int p = 0; p < 5; ++p) {
    int o = t + 256 * p;
    int d = o >> 7, c = o & 127;
    float s = 0.f;
    for (int f = 0; f < 128; ++f) s += V[d * 128 + f] * W1[f * 128 + c];
    U[o] = s * (1.f / 21.f);
  }
}

// ---------------- setup2: pack all B/A fragment blobs into ws ----------------
extern "C" __global__ void gnn_pack(const float* __restrict__ Wl,
                                    const float* __restrict__ Wout,
                                    const float* __restrict__ Uscr,
                                    char* __restrict__ G) {
  int unit = blockIdx.x, lane = threadIdx.x;
  int rsel = lane & 15, kh = lane >> 4;
  u16x8 r;
  char* dst;
  if (unit < 320) {                       // WB: ((l*8+nt)*4+ks)*2+pl
    int pl = unit & 1, ks = (unit >> 1) & 3, nt = (unit >> 3) & 7, l = unit >> 6;
    int col = nt * 16 + rsel, k0 = ks * 32 + kh * 8;
    const float* src = Wl + (l + 1) * 16384 + k0 * 128 + col;
#pragma unroll
    for (int i = 0; i < 8; ++i) {
      float v = src[i * 128] * (1.f / 21.f);
      unsigned short h = f2bf(v);
      r[i] = pl ? f2bf(v - bf2f(h)) : h;
    }
    dst = G + OFF_WB + unit * 1024 + lane * 16;
  } else if (unit < 338) {                // AB: nt*3+ks
    int u2 = unit - 320, nt = u2 / 3, ks = u2 % 3;
    r = makeAB(nt, ks, lane);
    dst = G + OFF_AB + u2 * 1024 + lane * 16;
  } else if (unit < 354) {                // UB: nt*2+pl
    int u2 = unit - 338, nt = u2 >> 1, pl = u2 & 1;
    int col = nt * 16 + rsel;
#pragma unroll
    for (int i = 0; i < 8; ++i) {
      int k = kh * 8 + i;
      float v = (k < 10) ? Uscr[k * 128 + col] : 0.f;
      unsigned short h = f2bf(v);
      r[i] = pl ? f2bf(v - bf2f(h)) : h;
    }
    dst = G + OFF_UB + u2 * 1024 + lane * 16;
  } else {                                // WOUT: ks*2+pl
    int u2 = unit - 354, ks = u2 >> 1, pl = u2 & 1;
    int col = rsel, k0 = ks * 32 + kh * 8;
#pragma unroll
    for (int i = 0; i < 8; ++i) {
      float v = (col < 9) ? Wout[(k0 + i) * 9 + col] : 0.f;
      unsigned short h = f2bf(v);
      r[i] = pl ? f2bf(v - bf2f(h)) : h;
    }
    dst = G + OFF_WOUT + u2 * 1024 + lane * 16;
  }
  *(u16x8*)dst = r;
}

// --------------------------------- main -------------------------------------
template <bool PRE>
__global__ void __launch_bounds__(512, 4)
gnn_main(const int* __restrict__ x, const float* __restrict__ Wl,
         const float* __restrict__ bl, const float* __restrict__ Wout,
         const float* __restrict__ bout, const float* __restrict__ ws,
         float* __restrict__ out, int nB) {
  extern __shared__ char lds[];
  const int t = threadIdx.x, lane = t & 63, w = t >> 6;   // w 0..7
  const int rsel = lane & 15, kh = lane >> 4;
  const char* G = (const char*)ws;
  const int b = blockIdx.x;

  const int ng = w & 1;                  // node triple: ntiles ng*3+{0,1,2}
  const int fg = w >> 1;                 // 0..3: out ftiles fg*2+{0,1};
                                         // agg ftile (per slice s) = s*4+fg

  // ---- persistent A+I B-frags (exact, hi only): 3 ntiles x 3 ks = 36 VGPR --
  u16x8 abf[3][3];
#pragma unroll
  for (int j = 0; j < 3; ++j)
#pragma unroll
    for (int ks = 0; ks < 3; ++ks) {
      if constexpr (PRE)
        abf[j][ks] = *(const u16x8*)(G + OFF_AB + (((ng * 3 + j) * 3 + ks) << 10) + lane * 16);
      else
        abf[j][ks] = makeAB(ng * 3 + j, ks, lane);
    }

  // per-slice W frags, HI ONLY (R13): [kk][jf] = 4 frags = 16 VGPR
  u16x8 wb[2][2];
  auto loadWBslice = [&](int blob, int s) {
#pragma unroll
    for (int kk = 0; kk < 2; ++kk)
#pragma unroll
      for (int jf = 0; jf < 2; ++jf) {
        if constexpr (PRE) {
          wb[kk][jf] = *(const u16x8*)(
              G + OFF_WB +
              ((((blob * 8 + (fg * 2 + jf)) * 4 + (s * 2 + kk)) * 2) << 10) +
              lane * 16);
        } else {
          int colw = (fg * 2 + jf) * 16 + rsel, k0 = (s * 2 + kk) * 32 + kh * 8;
          const float* src = Wl + (blob + 1) * 16384 + k0 * 128 + colw;
          u16x8 r;
#pragma unroll
          for (int i = 0; i < 8; ++i) r[i] = f2bf(src[i * 128] * (1.f / 21.f));
          wb[kk][jf] = r;
        }
      }
  };

  // ---- x cache + digit counts -> cntbuf ----
  if (t < 81) ((int*)(lds + XC))[t] = x[b * 81 + t];
  __syncthreads();
  if (t < 96) {
    unsigned short cnt[16];
#pragma unroll
    for (int d = 0; d < 16; ++d) cnt[d] = 0;
    if (t < 81) {
      const int* xs = (const int*)(lds + XC);
      int n = t, i = n / 9, j = n - 9 * i;
      int bi = (i / 3) * 3, bj = (j / 3) * 3;
      int rv[9], cv[9], bv[9], rb3[3], cb3[3];
#pragma unroll
      for (int k = 0; k < 9; ++k) rv[k] = xs[i * 9 + k];
#pragma unroll
      for (int k = 0; k < 9; ++k) cv[k] = xs[k * 9 + j];
#pragma unroll
      for (int r2 = 0; r2 < 3; ++r2)
#pragma unroll
        for (int c2 = 0; c2 < 3; ++c2) bv[r2 * 3 + c2] = xs[(bi + r2) * 9 + (bj + c2)];
#pragma unroll
      for (int k = 0; k < 3; ++k) rb3[k] = xs[i * 9 + bj + k];
#pragma unroll
      for (int k = 0; k < 3; ++k) cb3[k] = xs[(bi + k) * 9 + j];
#pragma unroll
      for (int d = 0; d < 10; ++d) {
        int c = 0;
#pragma unroll
        for (int k = 0; k < 9; ++k) c += (rv[k] == d) + (cv[k] == d) + (bv[k] == d);
#pragma unroll
        for (int k = 0; k < 3; ++k) c -= (rb3[k] == d) + (cb3[k] == d);
        cnt[d] = f2bf((float)c);         // integers <=21: exact in bf16
      }
    }
    u16x8 c0, c1, z;
#pragma unroll
    for (int e = 0; e < 8; ++e) { c0[e] = cnt[e]; c1[e] = cnt[8 + e]; z[e] = 0; }
    *(u16x8*)(lds + CNT + 0 * 1536 + t * 16) = c0;
    *(u16x8*)(lds + CNT + 1 * 1536 + t * 16) = c1;
    *(u16x8*)(lds + CNT + 2 * 1536 + t * 16) = z;
    *(u16x8*)(lds + CNT + 3 * 1536 + t * 16) = z;
  }
  __syncthreads();

  // ---- L1 GEMM: h1 = relu(Cnt @ U + b1) -> hbuf [feat][node] (3x2 tiles) ---
  {
    u16x8 ubf[2][2];                     // [jf][pl], dead after L1
#pragma unroll
    for (int jf = 0; jf < 2; ++jf)
#pragma unroll
      for (int pl = 0; pl < 2; ++pl) {
        if constexpr (PRE)
          ubf[jf][pl] = *(const u16x8*)(G + OFF_UB + (((fg * 2 + jf) * 2 + pl) << 10) + lane * 16);
        else {
          int col = (fg * 2 + jf) * 16 + rsel;
          u16x8 r;
#pragma unroll
          for (int i = 0; i < 8; ++i) {
            int k = kh * 8 + i;
            float v = (k < 10) ? ws[k * 128 + col] : 0.f;
            unsigned short h = f2bf(v);
            r[i] = pl ? f2bf(v - bf2f(h)) : h;
          }
          ubf[jf][pl] = r;
        }
      }
    float bL1[2];
#pragma unroll
    for (int jf = 0; jf < 2; ++jf) bL1[jf] = bl[(fg * 2 + jf) * 16 + rsel];

    f32x4 a1[3][2];
#pragma unroll
    for (int jn = 0; jn < 3; ++jn)
#pragma unroll
      for (int jf = 0; jf < 2; ++jf) a1[jn][jf] = f32x4{0.f, 0.f, 0.f, 0.f};
#pragma unroll
    for (int jn = 0; jn < 3; ++jn) {
      int node = (ng * 3 + jn) * 16 + rsel;
      u16x8 af = *(const u16x8*)(lds + CNT + kh * 1536 + node * 16);
#pragma unroll
      for (int jf = 0; jf < 2; ++jf) {
        a1[jn][jf] = mfma16(af, ubf[jf][0], a1[jn][jf]);
        a1[jn][jf] = mfma16(af, ubf[jf][1], a1[jn][jf]);
      }
    }
#pragma unroll
    for (int jn = 0; jn < 3; ++jn)
#pragma unroll
      for (int jf = 0; jf < 2; ++jf) {
        int node0 = (ng * 3 + jn) * 16 + kh * 4;
        int feat = (fg * 2 + jf) * 16 + rsel;
        f32x4 v;
#pragma unroll
        for (int r = 0; r < 4; ++r) {
          float u = fmaxf(a1[jn][jf][r] + bL1[jf], 0.f);
          v[r] = (node0 + r < 81) ? u : 0.f;
        }
        int base = (node0 >> 3) * 2048 + feat * 16 + (node0 & 7) * 2;
        *(u16x4*)(lds + HB + base) = cvt4(v);
      }
  }

  // agg of one 64-feat slice -> GS0/GS1 (1-product: h hi-only, A exact)
  auto do_agg_slice = [&](int s) {
    f32x4 ag[3];
#pragma unroll
    for (int j = 0; j < 3; ++j) ag[j] = f32x4{0.f, 0.f, 0.f, 0.f};
    int feat = (s * 4 + fg) * 16 + rsel;
#pragma unroll
    for (int ks = 0; ks < 3; ++ks) {
      int ba = (ks * 4 + kh) * 2048 + feat * 16;
      u16x8 ah = *(const u16x8*)(lds + HB + ba);
#pragma unroll
      for (int j = 0; j < 3; ++j) ag[j] = mfma16(ah, abf[j][ks], ag[j]);
    }
    int gsb = GS0 + s * 12288;
    int wbase = fg * 16 + kh * 4;        // within-slice floc base
    int wfb = wbase >> 3, woff = (wbase & 7) * 2;
#pragma unroll
    for (int j = 0; j < 3; ++j) {
      int node = (ng * 3 + j) * 16 + rsel;
      int ad = node * 128 + (((wfb + node) & 7) << 4) + woff;
      *(u16x4*)(lds + gsb + ad) = cvt4(ag[j]);
    }
  };

  // W accumulate one slice from GS[s] (1-product: g hi x W hi)
  f32x4 wc[3][2];
  auto do_W_slice = [&](int s) {
    int gsb = GS0 + s * 12288;
#pragma unroll
    for (int kk = 0; kk < 2; ++kk) {
#pragma unroll
      for (int jm = 0; jm < 3; ++jm) {
        int node = (ng * 3 + jm) * 16 + rsel;
        int ad = node * 128 + (((4 * kk + kh + node) & 7) << 4);
        u16x8 gh = *(const u16x8*)(lds + gsb + ad);
#pragma unroll
        for (int jf = 0; jf < 2; ++jf)
          wc[jm][jf] = mfma16(gh, wb[kk][jf], wc[jm][jf]);
      }
    }
  };

  // ---- GCN layers 2..5 (l=1..4): 2 slices, GS double-buffered, 3 barriers --
#pragma unroll 1
  for (int l = 1; l <= 4; ++l) {
    __syncthreads();                     // HB ready (prev epi)
    float bw[2];
#pragma unroll
    for (int jf = 0; jf < 2; ++jf) bw[jf] = bl[l * 128 + (fg * 2 + jf) * 16 + rsel];
#pragma unroll
    for (int jm = 0; jm < 3; ++jm)
#pragma unroll
      for (int jf = 0; jf < 2; ++jf) wc[jm][jf] = f32x4{0.f, 0.f, 0.f, 0.f};

    do_agg_slice(0);                     // -> GS0
    loadWBslice(l - 1, 0);               // hides under agg + barrier
    __syncthreads();                     // GS0 ready
    do_agg_slice(1);                     // -> GS1 (interleaves with W(0))
    do_W_slice(0);                       // reads GS0, uses wb (slice 0)
    loadWBslice(l - 1, 1);               // after W(0): wb regs free (WAR)
    __syncthreads();                     // GS1 ready (also: all HB reads done)
    do_W_slice(1);                       // reads GS1
    // epi: bias+relu+mask -> hbuf [feat][node] hi-only
#pragma unroll
    for (int jm = 0; jm < 3; ++jm)
#pragma unroll
      for (int jf = 0; jf < 2; ++jf) {
        int node0 = (ng * 3 + jm) * 16 + kh * 4;
        int feat = (fg * 2 + jf) * 16 + rsel;
        f32x4 v;
#pragma unroll
        for (int r = 0; r < 4; ++r) {
          float u = fmaxf(wc[jm][jf][r] + bw[jf], 0.f);
          v[r] = (node0 + r < 81) ? u : 0.f;
        }
        int base = (node0 >> 3) * 2048 + feat * 16 + (node0 & 7) * 2;
        *(u16x4*)(lds + HB + base) = cvt4(v);
      }
  }

  // ---- layer 6 (l=5), flipped: h6^T = (W/21)^T g^T, same 3-barrier shape ---
  __syncthreads();                       // HB (h5) ready
  {
    float b5[2][4];
#pragma unroll
    for (int jf = 0; jf < 2; ++jf)
#pragma unroll
      for (int r = 0; r < 4; ++r)
        b5[jf][r] = bl[5 * 128 + (fg * 2 + jf) * 16 + kh * 4 + r];
    f32x4 w6[2][3];
#pragma unroll
    for (int jf = 0; jf < 2; ++jf)
#pragma unroll
      for (int jn = 0; jn < 3; ++jn) w6[jf][jn] = f32x4{0.f, 0.f, 0.f, 0.f};

    auto do_flip_slice = [&](int s) {
      int gsb = GS0 + s * 12288;
#pragma unroll
      for (int kk = 0; kk < 2; ++kk) {
#pragma unroll
        for (int jn = 0; jn < 3; ++jn) {
          int node = (ng * 3 + jn) * 16 + rsel;
          int ad = node * 128 + (((4 * kk + kh + node) & 7) << 4);
          u16x8 gh = *(const u16x8*)(lds + gsb + ad);
#pragma unroll
          for (int jf = 0; jf < 2; ++jf)
            w6[jf][jn] = mfma16(wb[kk][jf], gh, w6[jf][jn]);
        }
      }
    };

    do_agg_slice(0);
    loadWBslice(4, 0);
    __syncthreads();                     // GS0 ready
    do_agg_slice(1);
    do_flip_slice(0);
    loadWBslice(4, 1);                   // after flip(0): wb regs free
    __syncthreads();                     // GS1 ready (all HB h5 reads done)
    do_flip_slice(1);
    // epi: C row=feat_out(4 consec), col=node -> h6 [node][feat] into HB
#pragma unroll
    for (int jf = 0; jf < 2; ++jf)
#pragma unroll
      for (int jn = 0; jn < 3; ++jn) {
        int node = (ng * 3 + jn) * 16 + rsel;
        int f0 = (fg * 2 + jf) * 16 + kh * 4;
        f32x4 v;
#pragma unroll
        for (int r = 0; r < 4; ++r) {
          float u = fmaxf(w6[jf][jn][r] + b5[jf][r], 0.f);
          v[r] = (node < 81) ? u : 0.f;
        }
        int base = (f0 >> 3) * 1536 + node * 16 + (f0 & 7) * 2;
        *(u16x4*)(lds + HB + base) = cvt4(v);
      }
  }

  // ---- output GEMM: logits = h6 @ Wout + bout (waves 0..5, 1 tile each) ----
  u16x8 wo[4][2];
  if (w < 6) {
#pragma unroll
    for (int ks = 0; ks < 4; ++ks)
#pragma unroll
      for (int pl = 0; pl < 2; ++pl) {
        if constexpr (PRE)
          wo[ks][pl] = *(const u16x8*)(G + OFF_WOUT + (ks * 2 + pl) * 1024 + lane * 16);
        else {
          int col = rsel, k0 = ks * 32 + kh * 8;
          u16x8 r;
#pragma unroll
          for (int i = 0; i < 8; ++i) {
            float v = (col < 9) ? Wout[(k0 + i) * 9 + col] : 0.f;
            unsigned short h = f2bf(v);
            r[i] = pl ? f2bf(v - bf2f(h)) : h;
          }
          wo[ks][pl] = r;
        }
      }
  }
  __syncthreads();
  if (w < 6) {
    f32x4 oc = f32x4{0.f, 0.f, 0.f, 0.f};
#pragma unroll
    for (int ks = 0; ks < 4; ++ks) {
      int node = w * 16 + rsel;
      int ba = (ks * 4 + kh) * 1536 + node * 16;
      u16x8 hh = *(const u16x8*)(lds + HB + ba);
      oc = mfma16(hh, wo[ks][0], oc);
      oc = mfma16(hh, wo[ks][1], oc);
    }
    int colo = rsel;
    if (colo < 9) {
      float bo = bout[colo];
#pragma unroll
      for (int r = 0; r < 4; ++r) {
        int node = w * 16 + kh * 4 + r;
        if (node < 81) out[b * 729 + node * 9 + colo] = oc[r] + bo;
      }
    }
  }
}

// ------------------------------- launcher ------------------------------------
extern "C" void kernel_launch(void* const* d_in, const int* in_sizes, int n_in,
                              void* d_out, int out_size, void* d_ws, size_t ws_size,
                              hipStream_t stream) {
  const int*   x    = (const int*)d_in[0];
  const float* Win  = (const float*)d_in[1];
  const float* bin  = (const float*)d_in[2];
  const float* Wl   = (const float*)d_in[3];
  const float* blay = (const float*)d_in[4];
  const float* Wout = (const float*)d_in[5];
  const float* bout = (const float*)d_in[6];
  float* out = (float*)d_out;
  int nB = in_sizes[0] / 81;

  bool pre = ws_size >= WS_NEED;
  gnn_setup<<<1, 256, 0, stream>>>(Win, bin, Wl, (float*)d_ws);     // U -> ws+0
  if (pre)
    gnn_pack<<<362, 64, 0, stream>>>(Wl, Wout, (const float*)d_ws, (char*)d_ws);

  if (pre) {
    hipFuncSetAttribute((const void*)gnn_main<true>,
                        hipFuncAttributeMaxDynamicSharedMemorySize, LDS_SZ);
    gnn_main<true><<<nB, 512, LDS_SZ, stream>>>(x, Wl, blay, Wout, bout,
                                                (const float*)d_ws, out, nB);
  } else {
    hipFuncSetAttribute((const void*)gnn_main<false>,
                        hipFuncAttributeMaxDynamicSharedMemorySize, LDS_SZ);
    gnn_main<false><<<nB, 512, LDS_SZ, stream>>>(x, Wl, blay, Wout, bout,
                                                 (const float*)d_ws, out, nB);
  }
}